// Round 6
// baseline (298.680 us; speedup 1.0000x reference)
//
#include <hip/hip_runtime.h>
#include <math.h>

// Problem constants (match reference)
#define NN   2048
#define NE   16384
#define NET  (NE + NN)   // 18432 edges incl. self loops
#define INF_ 128
#define OUTF 128
#define NH   4
#define OHF  8
#define NEG_SLOPE 0.2f
#define CAP  512         // max in-degree supported (actual max ~25 for this seed)

// fast symlog: |err| ~3e-7, fine vs harness tolerance
__device__ __forceinline__ float symlogf_(float v) {
    return copysignf(__logf(1.0f + fabsf(v)), v);
}

// ---------------------------------------------------------------------------
// K1: per-row sort (hybrid register/shuffle/LDS bitonic) + symlog +
//     conv1(1->8,k3,p1)+relu + conv2(8->16,k3,p1)+relu + mean-pool + fc(16->8).
//     Also writes slog = symlog(onehot) (unsorted) for the dot-attention.
//     Each thread owns 8 contiguous elements. Conv is column-streamed so only
//     3 h1-columns are live (no register-array spill to AGPR).
// ---------------------------------------------------------------------------
__global__ __launch_bounds__(256, 2) void k_sortconv(
    const float* __restrict__ onehot,
    const float* __restrict__ c1w, const float* __restrict__ c1b,
    const float* __restrict__ c2w, const float* __restrict__ c2b,
    const float* __restrict__ fcw, const float* __restrict__ fcb,
    float* __restrict__ slog, float* __restrict__ ohfeat) {
    __shared__ float soa[NN];         // SoA exchange buffer: soa[e*256 + t]
    __shared__ float bndL[4][2];      // wave-boundary passing (v6,v7 of lane63)
    __shared__ float bndR[4][2];      // (v0,v1 of lane0)
    __shared__ float red[64];
    __shared__ float pooled[16];
    const int t = threadIdx.x;
    const int r = blockIdx.x;
    const int b = t << 3;             // base element index of this thread
    const int wave = t >> 6, lane = t & 63;
    const float* row  = onehot + (size_t)r * NN;
    float*       srow = slog   + (size_t)r * NN;

    // ---- load 8 elements into registers; write symlog(unsorted) out ----
    float4 lo = ((const float4*)row)[t * 2];
    float4 hi = ((const float4*)row)[t * 2 + 1];
    float v[8] = {lo.x, lo.y, lo.z, lo.w, hi.x, hi.y, hi.z, hi.w};
    {
        float4 s0, s1;
        s0.x = symlogf_(v[0]); s0.y = symlogf_(v[1]);
        s0.z = symlogf_(v[2]); s0.w = symlogf_(v[3]);
        s1.x = symlogf_(v[4]); s1.y = symlogf_(v[5]);
        s1.z = symlogf_(v[6]); s1.w = symlogf_(v[7]);
        ((float4*)srow)[t * 2]     = s0;
        ((float4*)srow)[t * 2 + 1] = s1;
    }

    // compare-exchange: if up, x=min,y=max; else x=max,y=min
    auto cx = [](float& x, float& y, bool up) {
        float mn = fminf(x, y), mx = fmaxf(x, y);
        x = up ? mn : mx;
        y = up ? mx : mn;
    };

    // ---- in-register phases k=2,4,8 ----
    cx(v[0], v[1], true);  cx(v[2], v[3], false);
    cx(v[4], v[5], true);  cx(v[6], v[7], false);
    cx(v[0], v[2], true);  cx(v[1], v[3], true);
    cx(v[4], v[6], false); cx(v[5], v[7], false);
    cx(v[0], v[1], true);  cx(v[2], v[3], true);
    cx(v[4], v[5], false); cx(v[6], v[7], false);
    {
        const bool u8 = ((t & 1) == 0);
        cx(v[0], v[4], u8); cx(v[1], v[5], u8); cx(v[2], v[6], u8); cx(v[3], v[7], u8);
        cx(v[0], v[2], u8); cx(v[1], v[3], u8); cx(v[4], v[6], u8); cx(v[5], v[7], u8);
        cx(v[0], v[1], u8); cx(v[2], v[3], u8); cx(v[4], v[5], u8); cx(v[6], v[7], u8);
    }

    // ---- phases k=16..2048 ----
    for (int k = 16; k <= NN; k <<= 1) {
        const bool up = ((b & k) == 0);           // uniform per thread
        for (int j = k >> 1; j >= 8; j >>= 1) {
            const int pj = j >> 3;                // partner distance in threads
            const bool keepmin = (((t & pj) == 0) == up);
            if (pj <= 32) {
                #pragma unroll
                for (int e = 0; e < 8; e++) {
                    float p = __shfl_xor(v[e], pj, 64);
                    v[e] = keepmin ? fminf(v[e], p) : fmaxf(v[e], p);
                }
            } else {
                // cross-wave exchange via conflict-free SoA LDS (3 rounds total)
                __syncthreads();
                #pragma unroll
                for (int e = 0; e < 8; e++) soa[e * 256 + t] = v[e];
                __syncthreads();
                const int pt = t ^ pj;
                #pragma unroll
                for (int e = 0; e < 8; e++) {
                    float p = soa[e * 256 + pt];
                    v[e] = keepmin ? fminf(v[e], p) : fmaxf(v[e], p);
                }
            }
        }
        cx(v[0], v[4], up); cx(v[1], v[5], up); cx(v[2], v[6], up); cx(v[3], v[7], up);
        cx(v[0], v[2], up); cx(v[1], v[3], up); cx(v[4], v[6], up); cx(v[5], v[7], up);
        cx(v[0], v[1], up); cx(v[2], v[3], up); cx(v[4], v[5], up); cx(v[6], v[7], up);
    }

    // ---- symlog of sorted values (monotone => commutes with sort) ----
    #pragma unroll
    for (int e = 0; e < 8; e++) v[e] = symlogf_(v[e]);

    // ---- neighbor values via shuffles + wave-boundary LDS ----
    __syncthreads();   // soa no longer needed; reuse barriers for bnd
    if (lane == 63) { bndL[wave][0] = v[6]; bndL[wave][1] = v[7]; }
    if (lane == 0)  { bndR[wave][0] = v[0]; bndR[wave][1] = v[1]; }
    __syncthreads();
    float vm2 = __shfl_up(v[6], 1, 64);
    float vm1 = __shfl_up(v[7], 1, 64);
    float vp8 = __shfl_down(v[0], 1, 64);
    float vp9 = __shfl_down(v[1], 1, 64);
    if (lane == 0) {
        vm2 = wave ? bndL[wave - 1][0] : 0.0f;
        vm1 = wave ? bndL[wave - 1][1] : 0.0f;
    }
    if (lane == 63) {
        vp8 = (wave < 3) ? bndR[wave + 1][0] : 0.0f;
        vp9 = (wave < 3) ? bndR[wave + 1][1] : 0.0f;
    }

    // vin[m] = sorted symlog value at position b-2+m (0 outside range)
    float vin[12];
    vin[0] = vm2; vin[1] = vm1;
    #pragma unroll
    for (int e = 0; e < 8; e++) vin[2 + e] = v[e];
    vin[10] = vp8; vin[11] = vp9;

    // ---- column-streamed conv1+conv2+relu+pool ----
    // column I corresponds to position q = b-1+I (I=0..9)
    float cols[3][8];
    float sums[16];
    #pragma unroll
    for (int c = 0; c < 16; c++) sums[c] = 0.0f;

#define MKCOL(I, COL)                                                         \
    {                                                                         \
        const float xm = vin[(I)], xc = vin[(I) + 1], xp = vin[(I) + 2];      \
        _Pragma("unroll")                                                     \
        for (int c = 0; c < 8; c++) {                                         \
            float a = fmaf(c1w[c * 3 + 2], xp,                                \
                      fmaf(c1w[c * 3 + 1], xc,                                \
                      fmaf(c1w[c * 3 + 0], xm, c1b[c])));                     \
            (COL)[c] = fmaxf(a, 0.0f);                                        \
        }                                                                     \
        if ((I) == 0) {                                                       \
            if (t == 0) { _Pragma("unroll")                                   \
                for (int c = 0; c < 8; c++) (COL)[c] = 0.0f; }                \
        }                                                                     \
        if ((I) == 9) {                                                       \
            if (t == 255) { _Pragma("unroll")                                 \
                for (int c = 0; c < 8; c++) (COL)[c] = 0.0f; }                \
        }                                                                     \
    }

    MKCOL(0, cols[0]);
    MKCOL(1, cols[1]);
    #pragma unroll
    for (int ip = 0; ip < 8; ip++) {
        MKCOL(ip + 2, cols[(ip + 2) % 3]);
        const float* cA = cols[ip % 3];
        const float* cB = cols[(ip + 1) % 3];
        const float* cC = cols[(ip + 2) % 3];
        #pragma unroll
        for (int ch = 0; ch < 16; ch++) {
            float a = c2b[ch];
            #pragma unroll
            for (int c = 0; c < 8; c++) {
                a = fmaf(c2w[ch * 24 + c * 3 + 0], cA[c], a);
                a = fmaf(c2w[ch * 24 + c * 3 + 1], cB[c], a);
                a = fmaf(c2w[ch * 24 + c * 3 + 2], cC[c], a);
            }
            sums[ch] += fmaxf(a, 0.0f);
        }
    }
#undef MKCOL

    // ---- block reduction of 16 channel sums ----
    #pragma unroll
    for (int c = 0; c < 16; c++)
        for (int o = 32; o; o >>= 1) sums[c] += __shfl_down(sums[c], o);
    if (lane == 0)
        #pragma unroll
        for (int c = 0; c < 16; c++) red[wave * 16 + c] = sums[c];
    __syncthreads();
    if (t < 16)
        pooled[t] = (red[t] + red[16 + t] + red[32 + t] + red[48 + t]) * (1.0f / NN);
    __syncthreads();
    if (t < OHF) {
        float a = fcb[t];
        #pragma unroll
        for (int c = 0; c < 16; c++) a = fmaf(fcw[t * 16 + c], pooled[c], a);
        ohfeat[r * OHF + t] = a;
    }
}

// ---------------------------------------------------------------------------
// K2: xh = concat([x, oh_feat]) @ lin_w.T -> [N,512], fused with sa/ra
//     attention logits (saves a kernel + 4MB xh re-read).
// ---------------------------------------------------------------------------
__global__ __launch_bounds__(256) void k_xh(
    const float* __restrict__ x, const float* __restrict__ ohf,
    const float* __restrict__ lin_w, const float* __restrict__ att_l,
    const float* __restrict__ att_r, float* __restrict__ xh,
    float* __restrict__ sa, float* __restrict__ ra) {
    const int n0 = blockIdx.x * 4;
    __shared__ float xin[4][136];
    __shared__ float part[4][16];   // [wave][n*4 + g*2 + lr]
    const int tid = threadIdx.x;
    const int wave = tid >> 6, lane = tid & 63;
    for (int i = tid; i < 4 * 136; i += 256) {
        int nn = i / 136, k = i - nn * 136;
        xin[nn][k] = (k < INF_) ? x[(size_t)(n0+nn)*INF_ + k]
                                : ohf[(n0+nn)*OHF + (k - INF_)];
    }
    __syncthreads();
    float accl[2][4], accr[2][4];
    #pragma unroll
    for (int g = 0; g < 2; g++)
        #pragma unroll
        for (int n = 0; n < 4; n++) { accl[g][n] = 0.0f; accr[g][n] = 0.0f; }

    #pragma unroll
    for (int g = 0; g < 2; g++) {
        const int o = tid + g * 256;
        const float4* wr4 = (const float4*)(lin_w + (size_t)o * 136);
        float a0 = 0, a1 = 0, a2 = 0, a3 = 0;
        for (int kk = 0; kk < 34; kk++) {
            float4 w = wr4[kk];
            int k = kk * 4;
            a0 += w.x*xin[0][k] + w.y*xin[0][k+1] + w.z*xin[0][k+2] + w.w*xin[0][k+3];
            a1 += w.x*xin[1][k] + w.y*xin[1][k+1] + w.z*xin[1][k+2] + w.w*xin[1][k+3];
            a2 += w.x*xin[2][k] + w.y*xin[2][k+1] + w.z*xin[2][k+2] + w.w*xin[2][k+3];
            a3 += w.x*xin[3][k] + w.y*xin[3][k+1] + w.z*xin[3][k+2] + w.w*xin[3][k+3];
        }
        xh[(size_t)(n0+0)*512 + o] = a0;
        xh[(size_t)(n0+1)*512 + o] = a1;
        xh[(size_t)(n0+2)*512 + o] = a2;
        xh[(size_t)(n0+3)*512 + o] = a3;
        const float al = att_l[o], ar = att_r[o];
        accl[g][0] = fmaf(a0, al, accl[g][0]); accr[g][0] = fmaf(a0, ar, accr[g][0]);
        accl[g][1] = fmaf(a1, al, accl[g][1]); accr[g][1] = fmaf(a1, ar, accr[g][1]);
        accl[g][2] = fmaf(a2, al, accl[g][2]); accr[g][2] = fmaf(a2, ar, accr[g][2]);
        accl[g][3] = fmaf(a3, al, accl[g][3]); accr[g][3] = fmaf(a3, ar, accr[g][3]);
    }
    // wave-reduce the 16 accumulators (all lanes of a wave share the same head)
    #pragma unroll
    for (int g = 0; g < 2; g++)
        #pragma unroll
        for (int n = 0; n < 4; n++)
            for (int o = 32; o; o >>= 1) {
                accl[g][n] += __shfl_down(accl[g][n], o);
                accr[g][n] += __shfl_down(accr[g][n], o);
            }
    if (lane == 0) {
        #pragma unroll
        for (int g = 0; g < 2; g++)
            #pragma unroll
            for (int n = 0; n < 4; n++) {
                part[wave][n * 4 + g * 2 + 0] = accl[g][n];
                part[wave][n * 4 + g * 2 + 1] = accr[g][n];
            }
    }
    __syncthreads();
    if (tid < 32) {
        const int n = tid >> 3, rem = tid & 7, h = rem >> 1, lr = rem & 1;
        const int g = h >> 1, wp = (h & 1) * 2;
        const float val = part[wp][n * 4 + g * 2 + lr] + part[wp + 1][n * 4 + g * 2 + lr];
        if (lr == 0) sa[(n0 + n) * 4 + h] = val;
        else         ra[(n0 + n) * 4 + h] = val;
    }
}

// ---------------------------------------------------------------------------
// CSR build by destination (counting sort).
// ---------------------------------------------------------------------------
__global__ void k_count(const int* __restrict__ dst, int* __restrict__ deg) {
    int e = blockIdx.x * 256 + threadIdx.x;
    if (e < NET) {
        int d = (e < NE) ? dst[e] : (e - NE);
        atomicAdd(&deg[d], 1);
    }
}

__global__ __launch_bounds__(256) void k_scan(
    const int* __restrict__ deg, int* __restrict__ csr_off,
    int* __restrict__ csr_pos) {
    __shared__ int wsum[4];
    const int t = threadIdx.x, wave = t >> 6, lane = t & 63;
    int loc[8], s = 0;
    #pragma unroll
    for (int k = 0; k < 8; k++) { loc[k] = deg[t*8 + k]; s += loc[k]; }
    int x = s;   // inclusive scan within wave
    for (int o = 1; o < 64; o <<= 1) {
        int u = __shfl_up(x, o, 64);
        if (lane >= o) x += u;
    }
    if (lane == 63) wsum[wave] = x;
    __syncthreads();
    int off = 0;
    #pragma unroll
    for (int w = 0; w < 4; w++) if (w < wave) off += wsum[w];
    int base = off + x - s;   // exclusive prefix for this thread
    #pragma unroll
    for (int k = 0; k < 8; k++) {
        csr_off[t*8 + k] = base;
        csr_pos[t*8 + k] = base;
        base += loc[k];
    }
    if (t == 255) csr_off[NN] = off + x;
}

__global__ void k_fill(const int* __restrict__ dst, int* __restrict__ csr_pos,
                       int* __restrict__ csr_e) {
    int e = blockIdx.x * 256 + threadIdx.x;
    if (e < NET) {
        int d = (e < NE) ? dst[e] : (e - NE);
        int pos = atomicAdd(&csr_pos[d], 1);
        csr_e[pos] = e;
    }
}

// ---------------------------------------------------------------------------
// K4: per-edge raw attention: leaky_relu(sa[s]+ra[d]) / (slog[s].slog[d] + 1)
// ---------------------------------------------------------------------------
__global__ __launch_bounds__(256) void k_alpha(
    const int* __restrict__ src, const int* __restrict__ dst,
    const float* __restrict__ slog, const float* __restrict__ sa,
    const float* __restrict__ ra, float* __restrict__ alpha) {
    const int e = blockIdx.x;
    int s, d;
    if (e < NE) { s = src[e]; d = dst[e]; } else { s = d = e - NE; }
    const int tid = threadIdx.x;
    const float4* A = (const float4*)(slog + (size_t)s * NN);
    const float4* B = (const float4*)(slog + (size_t)d * NN);
    float4 a0 = A[tid*2], a1 = A[tid*2 + 1];
    float4 b0 = B[tid*2], b1 = B[tid*2 + 1];
    float p = a0.x*b0.x + a0.y*b0.y + a0.z*b0.z + a0.w*b0.w
            + a1.x*b1.x + a1.y*b1.y + a1.z*b1.z + a1.w*b1.w;
    for (int o = 32; o; o >>= 1) p += __shfl_down(p, o);
    __shared__ float ps[4];
    const int wave = tid >> 6, lane = tid & 63;
    if (lane == 0) ps[wave] = p;
    __syncthreads();
    if (tid == 0) {
        float dot  = ps[0] + ps[1] + ps[2] + ps[3];
        float datt = 1.0f / (dot + 1.0f);
        float4 out;
        float* po = (float*)&out;
        for (int h = 0; h < 4; h++) {
            float a = sa[s*4 + h] + ra[d*4 + h];
            a = (a >= 0.0f) ? a : NEG_SLOPE * a;
            po[h] = a * datt;
        }
        *(float4*)(alpha + (size_t)e * 4) = out;
    }
}

// ---------------------------------------------------------------------------
// K5: per destination node: segment softmax over incoming edges + weighted
//     aggregation of xh[s] rows. new_x = agg + bias.
// ---------------------------------------------------------------------------
__global__ __launch_bounds__(256) void k_soft_aggx(
    const int* __restrict__ src, const int* __restrict__ csr_off,
    const int* __restrict__ csr_e, const float* __restrict__ alpha,
    const float* __restrict__ xh, const float* __restrict__ bias,
    float* __restrict__ out_x) {
    const int d = blockIdx.x;
    const int begin = csr_off[d];
    int deg = csr_off[d + 1] - begin;
    if (deg > CAP) deg = CAP;   // unreachable for this input distribution
    __shared__ float wls[CAP * 4];
    __shared__ int   sls[CAP];
    const int tid = threadIdx.x;
    for (int t = tid; t < deg; t += 256) {
        int e = csr_e[begin + t];
        sls[t] = (e < NE) ? src[e] : (e - NE);
        float4 a = *(const float4*)(alpha + (size_t)e * 4);
        wls[t*4 + 0] = a.x; wls[t*4 + 1] = a.y;
        wls[t*4 + 2] = a.z; wls[t*4 + 3] = a.w;
    }
    __syncthreads();
    const int wave = tid >> 6, lane = tid & 63;
    if (wave < 4) {  // wave w owns head w
        float m = -3.4e38f;
        for (int t = lane; t < deg; t += 64) m = fmaxf(m, wls[t*4 + wave]);
        for (int o = 32; o; o >>= 1) m = fmaxf(m, __shfl_down(m, o));
        m = __shfl(m, 0);
        float s = 0.0f;
        for (int t = lane; t < deg; t += 64) {
            float ex = expf(wls[t*4 + wave] - m);
            wls[t*4 + wave] = ex;
            s += ex;
        }
        for (int o = 32; o; o >>= 1) s += __shfl_down(s, o);
        s = __shfl(s, 0);
        float inv = 1.0f / (s + 1e-16f);
        for (int t = lane; t < deg; t += 64) wls[t*4 + wave] *= inv;
    }
    __syncthreads();
    for (int ho = tid; ho < 512; ho += 256) {
        const int h = ho >> 7;
        float acc = 0.0f;
        for (int t = 0; t < deg; t++)
            acc += wls[t*4 + h] * xh[(size_t)sls[t] * 512 + ho];
        out_x[(size_t)d * 512 + ho] = acc + bias[ho];
    }
}

// ---------------------------------------------------------------------------
// K6: new_onehot = onehot + sum over incoming edges of onehot[s].
// ---------------------------------------------------------------------------
__global__ __launch_bounds__(256) void k_aggoh(
    const float* __restrict__ onehot, const int* __restrict__ src,
    const int* __restrict__ csr_off, const int* __restrict__ csr_e,
    float* __restrict__ out_oh) {
    const int d = blockIdx.x;
    const int begin = csr_off[d], end = csr_off[d + 1];
    const int tid = threadIdx.x;
    const float4* own = (const float4*)(onehot + (size_t)d * NN);
    float4 A = own[tid], B = own[tid + 256];
    for (int p = begin; p < end; p++) {
        int e = csr_e[p];
        int s = (e < NE) ? src[e] : (e - NE);
        const float4* r4 = (const float4*)(onehot + (size_t)s * NN);
        float4 u = r4[tid], v = r4[tid + 256];
        A.x += u.x; A.y += u.y; A.z += u.z; A.w += u.w;
        B.x += v.x; B.y += v.y; B.z += v.z; B.w += v.w;
    }
    float4* o4 = (float4*)(out_oh + (size_t)d * NN);
    o4[tid] = A; o4[tid + 256] = B;
}

// ---------------------------------------------------------------------------
extern "C" void kernel_launch(void* const* d_in, const int* in_sizes, int n_in,
                              void* d_out, int out_size, void* d_ws, size_t ws_size,
                              hipStream_t stream) {
    const float* x      = (const float*)d_in[0];
    const float* onehot = (const float*)d_in[1];
    const int*   src    = (const int*)d_in[2];
    const int*   dst    = (const int*)d_in[3];
    const float* lin_w  = (const float*)d_in[4];
    const float* att_l  = (const float*)d_in[5];
    const float* att_r  = (const float*)d_in[6];
    const float* bias   = (const float*)d_in[7];
    const float* c1w    = (const float*)d_in[8];
    const float* c1b    = (const float*)d_in[9];
    const float* c2w    = (const float*)d_in[10];
    const float* c2b    = (const float*)d_in[11];
    const float* fcw    = (const float*)d_in[12];
    const float* fcb    = (const float*)d_in[13];

    float* out_x  = (float*)d_out;                       // [N, 512]
    float* out_oh = out_x + (size_t)NN * (NH * OUTF);    // [N, N]

    // Workspace layout (~21.5 MB)
    float* ws    = (float*)d_ws;
    float* slog  = ws;                           // N*N
    float* xh    = slog + (size_t)NN * NN;       // N*512
    float* ohf   = xh   + (size_t)NN * 512;      // N*8
    float* sa    = ohf  + (size_t)NN * OHF;      // N*4
    float* ra    = sa   + (size_t)NN * NH;       // N*4
    float* alpha = ra   + (size_t)NN * NH;       // NET*4
    int* deg     = (int*)(alpha + (size_t)NET * 4);
    int* csr_off = deg + NN;                     // N+1
    int* csr_pos = csr_off + NN + 1;             // N
    int* csr_e   = csr_pos + NN;                 // NET

    hipMemsetAsync(deg, 0, NN * sizeof(int), stream);
    k_sortconv<<<NN, 256, 0, stream>>>(onehot, c1w, c1b, c2w, c2b, fcw, fcb, slog, ohf);
    k_count<<<(NET + 255) / 256, 256, 0, stream>>>(dst, deg);
    k_scan<<<1, 256, 0, stream>>>(deg, csr_off, csr_pos);
    k_fill<<<(NET + 255) / 256, 256, 0, stream>>>(dst, csr_pos, csr_e);
    k_xh<<<NN / 4, 256, 0, stream>>>(x, ohf, lin_w, att_l, att_r, xh, sa, ra);
    k_alpha<<<NET, 256, 0, stream>>>(src, dst, slog, sa, ra, alpha);
    k_soft_aggx<<<NN, 256, 0, stream>>>(src, csr_off, csr_e, alpha, xh, bias, out_x);
    k_aggoh<<<NN, 256, 0, stream>>>(onehot, src, csr_off, csr_e, out_oh);
}

// Round 7
// 292.175 us; speedup vs baseline: 1.0223x; 1.0223x over previous
//
#include <hip/hip_runtime.h>
#include <math.h>

// Problem constants (match reference)
#define NN   2048
#define NE   16384
#define NET  (NE + NN)   // 18432 edges incl. self loops
#define INF_ 128
#define OUTF 128
#define NH   4
#define OHF  8
#define NEG_SLOPE 0.2f
#define CAP  512         // max in-degree supported (actual max ~25 for this seed)

// fast symlog: |err| ~3e-7, fine vs harness tolerance
__device__ __forceinline__ float symlogf_(float v) {
    return copysignf(__logf(1.0f + fabsf(v)), v);
}

// ---------------------------------------------------------------------------
// K1: per-row sort (hybrid register/shuffle/LDS bitonic) + symlog +
//     conv1(1->8,k3,p1)+relu + conv2(8->16,k3,p1)+relu + mean-pool + fc(16->8).
//     Also writes slog = symlog(onehot) (unsorted) for the dot-attention.
//     Each thread owns 8 contiguous elements. Conv2 is weight-stationary:
//     h1 columns live in VGPRs, each channel's 24 weights loaded once (SGPR)
//     and reused across all 8 positions (192 FMAs per 24 loads).
// ---------------------------------------------------------------------------
__global__ __launch_bounds__(256, 2) void k_sortconv(
    const float* __restrict__ onehot,
    const float* __restrict__ c1w, const float* __restrict__ c1b,
    const float* __restrict__ c2w, const float* __restrict__ c2b,
    const float* __restrict__ fcw, const float* __restrict__ fcb,
    float* __restrict__ slog, float* __restrict__ ohfeat) {
    __shared__ float soa[NN];         // SoA exchange buffer: soa[e*256 + t]
    __shared__ float bndL[4][2];      // wave-boundary passing (v6,v7 of lane63)
    __shared__ float bndR[4][2];      // (v0,v1 of lane0)
    __shared__ float red[64];
    __shared__ float pooled[16];
    const int t = threadIdx.x;
    const int r = blockIdx.x;
    const int b = t << 3;             // base element index of this thread
    const int wave = t >> 6, lane = t & 63;
    const float* row  = onehot + (size_t)r * NN;
    float*       srow = slog   + (size_t)r * NN;

    // ---- load 8 elements into registers; write symlog(unsorted) out ----
    float4 lo = ((const float4*)row)[t * 2];
    float4 hi = ((const float4*)row)[t * 2 + 1];
    float v[8] = {lo.x, lo.y, lo.z, lo.w, hi.x, hi.y, hi.z, hi.w};
    {
        float4 s0, s1;
        s0.x = symlogf_(v[0]); s0.y = symlogf_(v[1]);
        s0.z = symlogf_(v[2]); s0.w = symlogf_(v[3]);
        s1.x = symlogf_(v[4]); s1.y = symlogf_(v[5]);
        s1.z = symlogf_(v[6]); s1.w = symlogf_(v[7]);
        ((float4*)srow)[t * 2]     = s0;
        ((float4*)srow)[t * 2 + 1] = s1;
    }

    // compare-exchange: if up, x=min,y=max; else x=max,y=min
    auto cx = [](float& x, float& y, bool up) {
        float mn = fminf(x, y), mx = fmaxf(x, y);
        x = up ? mn : mx;
        y = up ? mx : mn;
    };

    // ---- in-register phases k=2,4,8 ----
    cx(v[0], v[1], true);  cx(v[2], v[3], false);
    cx(v[4], v[5], true);  cx(v[6], v[7], false);
    cx(v[0], v[2], true);  cx(v[1], v[3], true);
    cx(v[4], v[6], false); cx(v[5], v[7], false);
    cx(v[0], v[1], true);  cx(v[2], v[3], true);
    cx(v[4], v[5], false); cx(v[6], v[7], false);
    {
        const bool u8 = ((t & 1) == 0);
        cx(v[0], v[4], u8); cx(v[1], v[5], u8); cx(v[2], v[6], u8); cx(v[3], v[7], u8);
        cx(v[0], v[2], u8); cx(v[1], v[3], u8); cx(v[4], v[6], u8); cx(v[5], v[7], u8);
        cx(v[0], v[1], u8); cx(v[2], v[3], u8); cx(v[4], v[5], u8); cx(v[6], v[7], u8);
    }

    // ---- phases k=16..2048 ----
    for (int k = 16; k <= NN; k <<= 1) {
        const bool up = ((b & k) == 0);           // uniform per thread
        for (int j = k >> 1; j >= 8; j >>= 1) {
            const int pj = j >> 3;                // partner distance in threads
            const bool keepmin = (((t & pj) == 0) == up);
            if (pj <= 32) {
                #pragma unroll
                for (int e = 0; e < 8; e++) {
                    float p = __shfl_xor(v[e], pj, 64);
                    v[e] = keepmin ? fminf(v[e], p) : fmaxf(v[e], p);
                }
            } else {
                // cross-wave exchange via conflict-free SoA LDS (3 rounds total)
                __syncthreads();
                #pragma unroll
                for (int e = 0; e < 8; e++) soa[e * 256 + t] = v[e];
                __syncthreads();
                const int pt = t ^ pj;
                #pragma unroll
                for (int e = 0; e < 8; e++) {
                    float p = soa[e * 256 + pt];
                    v[e] = keepmin ? fminf(v[e], p) : fmaxf(v[e], p);
                }
            }
        }
        cx(v[0], v[4], up); cx(v[1], v[5], up); cx(v[2], v[6], up); cx(v[3], v[7], up);
        cx(v[0], v[2], up); cx(v[1], v[3], up); cx(v[4], v[6], up); cx(v[5], v[7], up);
        cx(v[0], v[1], up); cx(v[2], v[3], up); cx(v[4], v[5], up); cx(v[6], v[7], up);
    }

    // ---- symlog of sorted values (monotone => commutes with sort) ----
    #pragma unroll
    for (int e = 0; e < 8; e++) v[e] = symlogf_(v[e]);

    // ---- neighbor values via shuffles + wave-boundary LDS ----
    __syncthreads();   // soa no longer needed; reuse barriers for bnd
    if (lane == 63) { bndL[wave][0] = v[6]; bndL[wave][1] = v[7]; }
    if (lane == 0)  { bndR[wave][0] = v[0]; bndR[wave][1] = v[1]; }
    __syncthreads();
    float vm2 = __shfl_up(v[6], 1, 64);
    float vm1 = __shfl_up(v[7], 1, 64);
    float vp8 = __shfl_down(v[0], 1, 64);
    float vp9 = __shfl_down(v[1], 1, 64);
    if (lane == 0) {
        vm2 = wave ? bndL[wave - 1][0] : 0.0f;
        vm1 = wave ? bndL[wave - 1][1] : 0.0f;
    }
    if (lane == 63) {
        vp8 = (wave < 3) ? bndR[wave + 1][0] : 0.0f;
        vp9 = (wave < 3) ? bndR[wave + 1][1] : 0.0f;
    }

    // vin[m] = sorted symlog value at position b-2+m (0 outside range)
    float vin[12];
    vin[0] = vm2; vin[1] = vm1;
    #pragma unroll
    for (int e = 0; e < 8; e++) vin[2 + e] = v[e];
    vin[10] = vp8; vin[11] = vp9;

    // ---- conv1: all 10 columns into VGPRs (static indices only) ----
    // column m corresponds to position q = b-1+m (m=0..9)
    float h1c[10][8];
    {
        // conv1 weights: 24 + 8 wave-uniform scalars, loaded once
        float w1[24], b1[8];
        #pragma unroll
        for (int q = 0; q < 24; q++) w1[q] = c1w[q];
        #pragma unroll
        for (int q = 0; q < 8; q++)  b1[q] = c1b[q];
        #pragma unroll
        for (int m = 0; m < 10; m++) {
            const float xm = vin[m], xc = vin[m + 1], xp = vin[m + 2];
            #pragma unroll
            for (int c = 0; c < 8; c++) {
                float a = fmaf(w1[c * 3 + 2], xp,
                          fmaf(w1[c * 3 + 1], xc,
                          fmaf(w1[c * 3 + 0], xm, b1[c])));
                h1c[m][c] = fmaxf(a, 0.0f);
            }
        }
        if (t == 0) {      // position q=-1 (zero pad)
            #pragma unroll
            for (int c = 0; c < 8; c++) h1c[0][c] = 0.0f;
        }
        if (t == 255) {    // position q=2048 (zero pad)
            #pragma unroll
            for (int c = 0; c < 8; c++) h1c[9][c] = 0.0f;
        }
    }

    // ---- conv2, weight-stationary: ch outer, 24 weights reused 8x ----
    float sums[16];
    #pragma unroll
    for (int ch = 0; ch < 16; ch++) {
        float wch[24];
        #pragma unroll
        for (int q = 0; q < 24; q++) wch[q] = c2w[ch * 24 + q];
        const float bb = c2b[ch];
        float acc = 0.0f;
        #pragma unroll
        for (int i = 0; i < 8; i++) {
            float a = bb;
            #pragma unroll
            for (int c = 0; c < 8; c++) {
                a = fmaf(wch[c * 3 + 0], h1c[i][c],     a);
                a = fmaf(wch[c * 3 + 1], h1c[i + 1][c], a);
                a = fmaf(wch[c * 3 + 2], h1c[i + 2][c], a);
            }
            acc += fmaxf(a, 0.0f);
        }
        sums[ch] = acc;
    }

    // ---- block reduction of 16 channel sums ----
    #pragma unroll
    for (int c = 0; c < 16; c++)
        for (int o = 32; o; o >>= 1) sums[c] += __shfl_down(sums[c], o);
    if (lane == 0)
        #pragma unroll
        for (int c = 0; c < 16; c++) red[wave * 16 + c] = sums[c];
    __syncthreads();
    if (t < 16)
        pooled[t] = (red[t] + red[16 + t] + red[32 + t] + red[48 + t]) * (1.0f / NN);
    __syncthreads();
    if (t < OHF) {
        float a = fcb[t];
        #pragma unroll
        for (int c = 0; c < 16; c++) a = fmaf(fcw[t * 16 + c], pooled[c], a);
        ohfeat[r * OHF + t] = a;
    }
}

// ---------------------------------------------------------------------------
// K2: xh = concat([x, oh_feat]) @ lin_w.T -> [N,512], fused with sa/ra
//     attention logits (saves a kernel + 4MB xh re-read).
// ---------------------------------------------------------------------------
__global__ __launch_bounds__(256) void k_xh(
    const float* __restrict__ x, const float* __restrict__ ohf,
    const float* __restrict__ lin_w, const float* __restrict__ att_l,
    const float* __restrict__ att_r, float* __restrict__ xh,
    float* __restrict__ sa, float* __restrict__ ra) {
    const int n0 = blockIdx.x * 4;
    __shared__ float xin[4][136];
    __shared__ float part[4][16];   // [wave][n*4 + g*2 + lr]
    const int tid = threadIdx.x;
    const int wave = tid >> 6, lane = tid & 63;
    for (int i = tid; i < 4 * 136; i += 256) {
        int nn = i / 136, k = i - nn * 136;
        xin[nn][k] = (k < INF_) ? x[(size_t)(n0+nn)*INF_ + k]
                                : ohf[(n0+nn)*OHF + (k - INF_)];
    }
    __syncthreads();
    float accl[2][4], accr[2][4];
    #pragma unroll
    for (int g = 0; g < 2; g++)
        #pragma unroll
        for (int n = 0; n < 4; n++) { accl[g][n] = 0.0f; accr[g][n] = 0.0f; }

    #pragma unroll
    for (int g = 0; g < 2; g++) {
        const int o = tid + g * 256;
        const float4* wr4 = (const float4*)(lin_w + (size_t)o * 136);
        float a0 = 0, a1 = 0, a2 = 0, a3 = 0;
        for (int kk = 0; kk < 34; kk++) {
            float4 w = wr4[kk];
            int k = kk * 4;
            a0 += w.x*xin[0][k] + w.y*xin[0][k+1] + w.z*xin[0][k+2] + w.w*xin[0][k+3];
            a1 += w.x*xin[1][k] + w.y*xin[1][k+1] + w.z*xin[1][k+2] + w.w*xin[1][k+3];
            a2 += w.x*xin[2][k] + w.y*xin[2][k+1] + w.z*xin[2][k+2] + w.w*xin[2][k+3];
            a3 += w.x*xin[3][k] + w.y*xin[3][k+1] + w.z*xin[3][k+2] + w.w*xin[3][k+3];
        }
        xh[(size_t)(n0+0)*512 + o] = a0;
        xh[(size_t)(n0+1)*512 + o] = a1;
        xh[(size_t)(n0+2)*512 + o] = a2;
        xh[(size_t)(n0+3)*512 + o] = a3;
        const float al = att_l[o], ar = att_r[o];
        accl[g][0] = fmaf(a0, al, accl[g][0]); accr[g][0] = fmaf(a0, ar, accr[g][0]);
        accl[g][1] = fmaf(a1, al, accl[g][1]); accr[g][1] = fmaf(a1, ar, accr[g][1]);
        accl[g][2] = fmaf(a2, al, accl[g][2]); accr[g][2] = fmaf(a2, ar, accr[g][2]);
        accl[g][3] = fmaf(a3, al, accl[g][3]); accr[g][3] = fmaf(a3, ar, accr[g][3]);
    }
    // wave-reduce the 16 accumulators (all lanes of a wave share the same head)
    #pragma unroll
    for (int g = 0; g < 2; g++)
        #pragma unroll
        for (int n = 0; n < 4; n++)
            for (int o = 32; o; o >>= 1) {
                accl[g][n] += __shfl_down(accl[g][n], o);
                accr[g][n] += __shfl_down(accr[g][n], o);
            }
    if (lane == 0) {
        #pragma unroll
        for (int g = 0; g < 2; g++)
            #pragma unroll
            for (int n = 0; n < 4; n++) {
                part[wave][n * 4 + g * 2 + 0] = accl[g][n];
                part[wave][n * 4 + g * 2 + 1] = accr[g][n];
            }
    }
    __syncthreads();
    if (tid < 32) {
        const int n = tid >> 3, rem = tid & 7, h = rem >> 1, lr = rem & 1;
        const int g = h >> 1, wp = (h & 1) * 2;
        const float val = part[wp][n * 4 + g * 2 + lr] + part[wp + 1][n * 4 + g * 2 + lr];
        if (lr == 0) sa[(n0 + n) * 4 + h] = val;
        else         ra[(n0 + n) * 4 + h] = val;
    }
}

// ---------------------------------------------------------------------------
// CSR build by destination (counting sort).
// ---------------------------------------------------------------------------
__global__ void k_count(const int* __restrict__ dst, int* __restrict__ deg) {
    int e = blockIdx.x * 256 + threadIdx.x;
    if (e < NET) {
        int d = (e < NE) ? dst[e] : (e - NE);
        atomicAdd(&deg[d], 1);
    }
}

__global__ __launch_bounds__(256) void k_scan(
    const int* __restrict__ deg, int* __restrict__ csr_off,
    int* __restrict__ csr_pos) {
    __shared__ int wsum[4];
    const int t = threadIdx.x, wave = t >> 6, lane = t & 63;
    int loc[8], s = 0;
    #pragma unroll
    for (int k = 0; k < 8; k++) { loc[k] = deg[t*8 + k]; s += loc[k]; }
    int x = s;   // inclusive scan within wave
    for (int o = 1; o < 64; o <<= 1) {
        int u = __shfl_up(x, o, 64);
        if (lane >= o) x += u;
    }
    if (lane == 63) wsum[wave] = x;
    __syncthreads();
    int off = 0;
    #pragma unroll
    for (int w = 0; w < 4; w++) if (w < wave) off += wsum[w];
    int base = off + x - s;   // exclusive prefix for this thread
    #pragma unroll
    for (int k = 0; k < 8; k++) {
        csr_off[t*8 + k] = base;
        csr_pos[t*8 + k] = base;
        base += loc[k];
    }
    if (t == 255) csr_off[NN] = off + x;
}

__global__ void k_fill(const int* __restrict__ dst, int* __restrict__ csr_pos,
                       int* __restrict__ csr_e) {
    int e = blockIdx.x * 256 + threadIdx.x;
    if (e < NET) {
        int d = (e < NE) ? dst[e] : (e - NE);
        int pos = atomicAdd(&csr_pos[d], 1);
        csr_e[pos] = e;
    }
}

// ---------------------------------------------------------------------------
// K4: per-edge raw attention: leaky_relu(sa[s]+ra[d]) / (slog[s].slog[d] + 1)
// ---------------------------------------------------------------------------
__global__ __launch_bounds__(256) void k_alpha(
    const int* __restrict__ src, const int* __restrict__ dst,
    const float* __restrict__ slog, const float* __restrict__ sa,
    const float* __restrict__ ra, float* __restrict__ alpha) {
    const int e = blockIdx.x;
    int s, d;
    if (e < NE) { s = src[e]; d = dst[e]; } else { s = d = e - NE; }
    const int tid = threadIdx.x;
    const float4* A = (const float4*)(slog + (size_t)s * NN);
    const float4* B = (const float4*)(slog + (size_t)d * NN);
    float4 a0 = A[tid*2], a1 = A[tid*2 + 1];
    float4 b0 = B[tid*2], b1 = B[tid*2 + 1];
    float p = a0.x*b0.x + a0.y*b0.y + a0.z*b0.z + a0.w*b0.w
            + a1.x*b1.x + a1.y*b1.y + a1.z*b1.z + a1.w*b1.w;
    for (int o = 32; o; o >>= 1) p += __shfl_down(p, o);
    __shared__ float ps[4];
    const int wave = tid >> 6, lane = tid & 63;
    if (lane == 0) ps[wave] = p;
    __syncthreads();
    if (tid == 0) {
        float dot  = ps[0] + ps[1] + ps[2] + ps[3];
        float datt = 1.0f / (dot + 1.0f);
        float4 out;
        float* po = (float*)&out;
        for (int h = 0; h < 4; h++) {
            float a = sa[s*4 + h] + ra[d*4 + h];
            a = (a >= 0.0f) ? a : NEG_SLOPE * a;
            po[h] = a * datt;
        }
        *(float4*)(alpha + (size_t)e * 4) = out;
    }
}

// ---------------------------------------------------------------------------
// K5: per destination node: segment softmax over incoming edges + weighted
//     aggregation of xh[s] rows. new_x = agg + bias.
// ---------------------------------------------------------------------------
__global__ __launch_bounds__(256) void k_soft_aggx(
    const int* __restrict__ src, const int* __restrict__ csr_off,
    const int* __restrict__ csr_e, const float* __restrict__ alpha,
    const float* __restrict__ xh, const float* __restrict__ bias,
    float* __restrict__ out_x) {
    const int d = blockIdx.x;
    const int begin = csr_off[d];
    int deg = csr_off[d + 1] - begin;
    if (deg > CAP) deg = CAP;   // unreachable for this input distribution
    __shared__ float wls[CAP * 4];
    __shared__ int   sls[CAP];
    const int tid = threadIdx.x;
    for (int t = tid; t < deg; t += 256) {
        int e = csr_e[begin + t];
        sls[t] = (e < NE) ? src[e] : (e - NE);
        float4 a = *(const float4*)(alpha + (size_t)e * 4);
        wls[t*4 + 0] = a.x; wls[t*4 + 1] = a.y;
        wls[t*4 + 2] = a.z; wls[t*4 + 3] = a.w;
    }
    __syncthreads();
    const int wave = tid >> 6, lane = tid & 63;
    if (wave < 4) {  // wave w owns head w
        float m = -3.4e38f;
        for (int t = lane; t < deg; t += 64) m = fmaxf(m, wls[t*4 + wave]);
        for (int o = 32; o; o >>= 1) m = fmaxf(m, __shfl_down(m, o));
        m = __shfl(m, 0);
        float s = 0.0f;
        for (int t = lane; t < deg; t += 64) {
            float ex = expf(wls[t*4 + wave] - m);
            wls[t*4 + wave] = ex;
            s += ex;
        }
        for (int o = 32; o; o >>= 1) s += __shfl_down(s, o);
        s = __shfl(s, 0);
        float inv = 1.0f / (s + 1e-16f);
        for (int t = lane; t < deg; t += 64) wls[t*4 + wave] *= inv;
    }
    __syncthreads();
    for (int ho = tid; ho < 512; ho += 256) {
        const int h = ho >> 7;
        float acc = 0.0f;
        for (int t = 0; t < deg; t++)
            acc += wls[t*4 + h] * xh[(size_t)sls[t] * 512 + ho];
        out_x[(size_t)d * 512 + ho] = acc + bias[ho];
    }
}

// ---------------------------------------------------------------------------
// K6: new_onehot = onehot + sum over incoming edges of onehot[s].
// ---------------------------------------------------------------------------
__global__ __launch_bounds__(256) void k_aggoh(
    const float* __restrict__ onehot, const int* __restrict__ src,
    const int* __restrict__ csr_off, const int* __restrict__ csr_e,
    float* __restrict__ out_oh) {
    const int d = blockIdx.x;
    const int begin = csr_off[d], end = csr_off[d + 1];
    const int tid = threadIdx.x;
    const float4* own = (const float4*)(onehot + (size_t)d * NN);
    float4 A = own[tid], B = own[tid + 256];
    for (int p = begin; p < end; p++) {
        int e = csr_e[p];
        int s = (e < NE) ? src[e] : (e - NE);
        const float4* r4 = (const float4*)(onehot + (size_t)s * NN);
        float4 u = r4[tid], v = r4[tid + 256];
        A.x += u.x; A.y += u.y; A.z += u.z; A.w += u.w;
        B.x += v.x; B.y += v.y; B.z += v.z; B.w += v.w;
    }
    float4* o4 = (float4*)(out_oh + (size_t)d * NN);
    o4[tid] = A; o4[tid + 256] = B;
}

// ---------------------------------------------------------------------------
extern "C" void kernel_launch(void* const* d_in, const int* in_sizes, int n_in,
                              void* d_out, int out_size, void* d_ws, size_t ws_size,
                              hipStream_t stream) {
    const float* x      = (const float*)d_in[0];
    const float* onehot = (const float*)d_in[1];
    const int*   src    = (const int*)d_in[2];
    const int*   dst    = (const int*)d_in[3];
    const float* lin_w  = (const float*)d_in[4];
    const float* att_l  = (const float*)d_in[5];
    const float* att_r  = (const float*)d_in[6];
    const float* bias   = (const float*)d_in[7];
    const float* c1w    = (const float*)d_in[8];
    const float* c1b    = (const float*)d_in[9];
    const float* c2w    = (const float*)d_in[10];
    const float* c2b    = (const float*)d_in[11];
    const float* fcw    = (const float*)d_in[12];
    const float* fcb    = (const float*)d_in[13];

    float* out_x  = (float*)d_out;                       // [N, 512]
    float* out_oh = out_x + (size_t)NN * (NH * OUTF);    // [N, N]

    // Workspace layout (~21.5 MB)
    float* ws    = (float*)d_ws;
    float* slog  = ws;                           // N*N
    float* xh    = slog + (size_t)NN * NN;       // N*512
    float* ohf   = xh   + (size_t)NN * 512;      // N*8
    float* sa    = ohf  + (size_t)NN * OHF;      // N*4
    float* ra    = sa   + (size_t)NN * NH;       // N*4
    float* alpha = ra   + (size_t)NN * NH;       // NET*4
    int* deg     = (int*)(alpha + (size_t)NET * 4);
    int* csr_off = deg + NN;                     // N+1
    int* csr_pos = csr_off + NN + 1;             // N
    int* csr_e   = csr_pos + NN;                 // NET

    hipMemsetAsync(deg, 0, NN * sizeof(int), stream);
    k_sortconv<<<NN, 256, 0, stream>>>(onehot, c1w, c1b, c2w, c2b, fcw, fcb, slog, ohf);
    k_count<<<(NET + 255) / 256, 256, 0, stream>>>(dst, deg);
    k_scan<<<1, 256, 0, stream>>>(deg, csr_off, csr_pos);
    k_fill<<<(NET + 255) / 256, 256, 0, stream>>>(dst, csr_pos, csr_e);
    k_xh<<<NN / 4, 256, 0, stream>>>(x, ohf, lin_w, att_l, att_r, xh, sa, ra);
    k_alpha<<<NET, 256, 0, stream>>>(src, dst, slog, sa, ra, alpha);
    k_soft_aggx<<<NN, 256, 0, stream>>>(src, csr_off, csr_e, alpha, xh, bias, out_x);
    k_aggoh<<<NN, 256, 0, stream>>>(onehot, src, csr_off, csr_e, out_oh);
}

// Round 8
// 292.056 us; speedup vs baseline: 1.0227x; 1.0004x over previous
//
#include <hip/hip_runtime.h>
#include <math.h>

// Problem constants (match reference)
#define NN   2048
#define NE   16384
#define NET  (NE + NN)   // 18432 edges incl. self loops
#define INF_ 128
#define OUTF 128
#define NH   4
#define OHF  8
#define NEG_SLOPE 0.2f
#define CAP  512         // max in-degree supported (actual max ~25 for this seed)

// fast symlog: |err| ~3e-7, fine vs harness tolerance
__device__ __forceinline__ float symlogf_(float v) {
    return copysignf(__logf(1.0f + fabsf(v)), v);
}

// ---------------------------------------------------------------------------
// K1: per-row sort (hybrid register/shuffle/LDS bitonic) + symlog +
//     conv1(1->8,k3,p1)+relu + conv2(8->16,k3,p1)+relu + mean-pool + fc(16->8).
//     Also writes slog = symlog(onehot) (unsorted) for the dot-attention.
//     UNCHANGED from round 7 (120 us measured).
// ---------------------------------------------------------------------------
__global__ __launch_bounds__(256, 2) void k_sortconv(
    const float* __restrict__ onehot,
    const float* __restrict__ c1w, const float* __restrict__ c1b,
    const float* __restrict__ c2w, const float* __restrict__ c2b,
    const float* __restrict__ fcw, const float* __restrict__ fcb,
    float* __restrict__ slog, float* __restrict__ ohfeat) {
    __shared__ float soa[NN];         // SoA exchange buffer: soa[e*256 + t]
    __shared__ float bndL[4][2];      // wave-boundary passing (v6,v7 of lane63)
    __shared__ float bndR[4][2];      // (v0,v1 of lane0)
    __shared__ float red[64];
    __shared__ float pooled[16];
    const int t = threadIdx.x;
    const int r = blockIdx.x;
    const int b = t << 3;             // base element index of this thread
    const int wave = t >> 6, lane = t & 63;
    const float* row  = onehot + (size_t)r * NN;
    float*       srow = slog   + (size_t)r * NN;

    // ---- load 8 elements into registers; write symlog(unsorted) out ----
    float4 lo = ((const float4*)row)[t * 2];
    float4 hi = ((const float4*)row)[t * 2 + 1];
    float v[8] = {lo.x, lo.y, lo.z, lo.w, hi.x, hi.y, hi.z, hi.w};
    {
        float4 s0, s1;
        s0.x = symlogf_(v[0]); s0.y = symlogf_(v[1]);
        s0.z = symlogf_(v[2]); s0.w = symlogf_(v[3]);
        s1.x = symlogf_(v[4]); s1.y = symlogf_(v[5]);
        s1.z = symlogf_(v[6]); s1.w = symlogf_(v[7]);
        ((float4*)srow)[t * 2]     = s0;
        ((float4*)srow)[t * 2 + 1] = s1;
    }

    // compare-exchange: if up, x=min,y=max; else x=max,y=min
    auto cx = [](float& x, float& y, bool up) {
        float mn = fminf(x, y), mx = fmaxf(x, y);
        x = up ? mn : mx;
        y = up ? mx : mn;
    };

    // ---- in-register phases k=2,4,8 ----
    cx(v[0], v[1], true);  cx(v[2], v[3], false);
    cx(v[4], v[5], true);  cx(v[6], v[7], false);
    cx(v[0], v[2], true);  cx(v[1], v[3], true);
    cx(v[4], v[6], false); cx(v[5], v[7], false);
    cx(v[0], v[1], true);  cx(v[2], v[3], true);
    cx(v[4], v[5], false); cx(v[6], v[7], false);
    {
        const bool u8 = ((t & 1) == 0);
        cx(v[0], v[4], u8); cx(v[1], v[5], u8); cx(v[2], v[6], u8); cx(v[3], v[7], u8);
        cx(v[0], v[2], u8); cx(v[1], v[3], u8); cx(v[4], v[6], u8); cx(v[5], v[7], u8);
        cx(v[0], v[1], u8); cx(v[2], v[3], u8); cx(v[4], v[5], u8); cx(v[6], v[7], u8);
    }

    // ---- phases k=16..2048 ----
    for (int k = 16; k <= NN; k <<= 1) {
        const bool up = ((b & k) == 0);           // uniform per thread
        for (int j = k >> 1; j >= 8; j >>= 1) {
            const int pj = j >> 3;                // partner distance in threads
            const bool keepmin = (((t & pj) == 0) == up);
            if (pj <= 32) {
                #pragma unroll
                for (int e = 0; e < 8; e++) {
                    float p = __shfl_xor(v[e], pj, 64);
                    v[e] = keepmin ? fminf(v[e], p) : fmaxf(v[e], p);
                }
            } else {
                // cross-wave exchange via conflict-free SoA LDS (3 rounds total)
                __syncthreads();
                #pragma unroll
                for (int e = 0; e < 8; e++) soa[e * 256 + t] = v[e];
                __syncthreads();
                const int pt = t ^ pj;
                #pragma unroll
                for (int e = 0; e < 8; e++) {
                    float p = soa[e * 256 + pt];
                    v[e] = keepmin ? fminf(v[e], p) : fmaxf(v[e], p);
                }
            }
        }
        cx(v[0], v[4], up); cx(v[1], v[5], up); cx(v[2], v[6], up); cx(v[3], v[7], up);
        cx(v[0], v[2], up); cx(v[1], v[3], up); cx(v[4], v[6], up); cx(v[5], v[7], up);
        cx(v[0], v[1], up); cx(v[2], v[3], up); cx(v[4], v[5], up); cx(v[6], v[7], up);
    }

    // ---- symlog of sorted values (monotone => commutes with sort) ----
    #pragma unroll
    for (int e = 0; e < 8; e++) v[e] = symlogf_(v[e]);

    // ---- neighbor values via shuffles + wave-boundary LDS ----
    __syncthreads();   // soa no longer needed; reuse barriers for bnd
    if (lane == 63) { bndL[wave][0] = v[6]; bndL[wave][1] = v[7]; }
    if (lane == 0)  { bndR[wave][0] = v[0]; bndR[wave][1] = v[1]; }
    __syncthreads();
    float vm2 = __shfl_up(v[6], 1, 64);
    float vm1 = __shfl_up(v[7], 1, 64);
    float vp8 = __shfl_down(v[0], 1, 64);
    float vp9 = __shfl_down(v[1], 1, 64);
    if (lane == 0) {
        vm2 = wave ? bndL[wave - 1][0] : 0.0f;
        vm1 = wave ? bndL[wave - 1][1] : 0.0f;
    }
    if (lane == 63) {
        vp8 = (wave < 3) ? bndR[wave + 1][0] : 0.0f;
        vp9 = (wave < 3) ? bndR[wave + 1][1] : 0.0f;
    }

    // vin[m] = sorted symlog value at position b-2+m (0 outside range)
    float vin[12];
    vin[0] = vm2; vin[1] = vm1;
    #pragma unroll
    for (int e = 0; e < 8; e++) vin[2 + e] = v[e];
    vin[10] = vp8; vin[11] = vp9;

    // ---- conv1: all 10 columns into VGPRs (static indices only) ----
    float h1c[10][8];
    {
        float w1[24], b1[8];
        #pragma unroll
        for (int q = 0; q < 24; q++) w1[q] = c1w[q];
        #pragma unroll
        for (int q = 0; q < 8; q++)  b1[q] = c1b[q];
        #pragma unroll
        for (int m = 0; m < 10; m++) {
            const float xm = vin[m], xc = vin[m + 1], xp = vin[m + 2];
            #pragma unroll
            for (int c = 0; c < 8; c++) {
                float a = fmaf(w1[c * 3 + 2], xp,
                          fmaf(w1[c * 3 + 1], xc,
                          fmaf(w1[c * 3 + 0], xm, b1[c])));
                h1c[m][c] = fmaxf(a, 0.0f);
            }
        }
        if (t == 0) {      // position q=-1 (zero pad)
            #pragma unroll
            for (int c = 0; c < 8; c++) h1c[0][c] = 0.0f;
        }
        if (t == 255) {    // position q=2048 (zero pad)
            #pragma unroll
            for (int c = 0; c < 8; c++) h1c[9][c] = 0.0f;
        }
    }

    // ---- conv2, weight-stationary: ch outer, 24 weights reused 8x ----
    float sums[16];
    #pragma unroll
    for (int ch = 0; ch < 16; ch++) {
        float wch[24];
        #pragma unroll
        for (int q = 0; q < 24; q++) wch[q] = c2w[ch * 24 + q];
        const float bb = c2b[ch];
        float acc = 0.0f;
        #pragma unroll
        for (int i = 0; i < 8; i++) {
            float a = bb;
            #pragma unroll
            for (int c = 0; c < 8; c++) {
                a = fmaf(wch[c * 3 + 0], h1c[i][c],     a);
                a = fmaf(wch[c * 3 + 1], h1c[i + 1][c], a);
                a = fmaf(wch[c * 3 + 2], h1c[i + 2][c], a);
            }
            acc += fmaxf(a, 0.0f);
        }
        sums[ch] = acc;
    }

    // ---- block reduction of 16 channel sums ----
    #pragma unroll
    for (int c = 0; c < 16; c++)
        for (int o = 32; o; o >>= 1) sums[c] += __shfl_down(sums[c], o);
    if (lane == 0)
        #pragma unroll
        for (int c = 0; c < 16; c++) red[wave * 16 + c] = sums[c];
    __syncthreads();
    if (t < 16)
        pooled[t] = (red[t] + red[16 + t] + red[32 + t] + red[48 + t]) * (1.0f / NN);
    __syncthreads();
    if (t < OHF) {
        float a = fcb[t];
        #pragma unroll
        for (int c = 0; c < 16; c++) a = fmaf(fcw[t * 16 + c], pooled[c], a);
        ohfeat[r * OHF + t] = a;
    }
}

// ---------------------------------------------------------------------------
// K2: xh = concat([x, oh_feat]) @ lin_w.T -> [N,512], fused with sa/ra
//     attention logits. UNCHANGED from round 7.
// ---------------------------------------------------------------------------
__global__ __launch_bounds__(256) void k_xh(
    const float* __restrict__ x, const float* __restrict__ ohf,
    const float* __restrict__ lin_w, const float* __restrict__ att_l,
    const float* __restrict__ att_r, float* __restrict__ xh,
    float* __restrict__ sa, float* __restrict__ ra) {
    const int n0 = blockIdx.x * 4;
    __shared__ float xin[4][136];
    __shared__ float part[4][16];   // [wave][n*4 + g*2 + lr]
    const int tid = threadIdx.x;
    const int wave = tid >> 6, lane = tid & 63;
    for (int i = tid; i < 4 * 136; i += 256) {
        int nn = i / 136, k = i - nn * 136;
        xin[nn][k] = (k < INF_) ? x[(size_t)(n0+nn)*INF_ + k]
                                : ohf[(n0+nn)*OHF + (k - INF_)];
    }
    __syncthreads();
    float accl[2][4], accr[2][4];
    #pragma unroll
    for (int g = 0; g < 2; g++)
        #pragma unroll
        for (int n = 0; n < 4; n++) { accl[g][n] = 0.0f; accr[g][n] = 0.0f; }

    #pragma unroll
    for (int g = 0; g < 2; g++) {
        const int o = tid + g * 256;
        const float4* wr4 = (const float4*)(lin_w + (size_t)o * 136);
        float a0 = 0, a1 = 0, a2 = 0, a3 = 0;
        for (int kk = 0; kk < 34; kk++) {
            float4 w = wr4[kk];
            int k = kk * 4;
            a0 += w.x*xin[0][k] + w.y*xin[0][k+1] + w.z*xin[0][k+2] + w.w*xin[0][k+3];
            a1 += w.x*xin[1][k] + w.y*xin[1][k+1] + w.z*xin[1][k+2] + w.w*xin[1][k+3];
            a2 += w.x*xin[2][k] + w.y*xin[2][k+1] + w.z*xin[2][k+2] + w.w*xin[2][k+3];
            a3 += w.x*xin[3][k] + w.y*xin[3][k+1] + w.z*xin[3][k+2] + w.w*xin[3][k+3];
        }
        xh[(size_t)(n0+0)*512 + o] = a0;
        xh[(size_t)(n0+1)*512 + o] = a1;
        xh[(size_t)(n0+2)*512 + o] = a2;
        xh[(size_t)(n0+3)*512 + o] = a3;
        const float al = att_l[o], ar = att_r[o];
        accl[g][0] = fmaf(a0, al, accl[g][0]); accr[g][0] = fmaf(a0, ar, accr[g][0]);
        accl[g][1] = fmaf(a1, al, accl[g][1]); accr[g][1] = fmaf(a1, ar, accr[g][1]);
        accl[g][2] = fmaf(a2, al, accl[g][2]); accr[g][2] = fmaf(a2, ar, accr[g][2]);
        accl[g][3] = fmaf(a3, al, accl[g][3]); accr[g][3] = fmaf(a3, ar, accr[g][3]);
    }
    // wave-reduce the 16 accumulators (all lanes of a wave share the same head)
    #pragma unroll
    for (int g = 0; g < 2; g++)
        #pragma unroll
        for (int n = 0; n < 4; n++)
            for (int o = 32; o; o >>= 1) {
                accl[g][n] += __shfl_down(accl[g][n], o);
                accr[g][n] += __shfl_down(accr[g][n], o);
            }
    if (lane == 0) {
        #pragma unroll
        for (int g = 0; g < 2; g++)
            #pragma unroll
            for (int n = 0; n < 4; n++) {
                part[wave][n * 4 + g * 2 + 0] = accl[g][n];
                part[wave][n * 4 + g * 2 + 1] = accr[g][n];
            }
    }
    __syncthreads();
    if (tid < 32) {
        const int n = tid >> 3, rem = tid & 7, h = rem >> 1, lr = rem & 1;
        const int g = h >> 1, wp = (h & 1) * 2;
        const float val = part[wp][n * 4 + g * 2 + lr] + part[wp + 1][n * 4 + g * 2 + lr];
        if (lr == 0) sa[(n0 + n) * 4 + h] = val;
        else         ra[(n0 + n) * 4 + h] = val;
    }
}

// ---------------------------------------------------------------------------
// CSR build by destination (counting sort). UNCHANGED.
// ---------------------------------------------------------------------------
__global__ void k_count(const int* __restrict__ dst, int* __restrict__ deg) {
    int e = blockIdx.x * 256 + threadIdx.x;
    if (e < NET) {
        int d = (e < NE) ? dst[e] : (e - NE);
        atomicAdd(&deg[d], 1);
    }
}

__global__ __launch_bounds__(256) void k_scan(
    const int* __restrict__ deg, int* __restrict__ csr_off,
    int* __restrict__ csr_pos) {
    __shared__ int wsum[4];
    const int t = threadIdx.x, wave = t >> 6, lane = t & 63;
    int loc[8], s = 0;
    #pragma unroll
    for (int k = 0; k < 8; k++) { loc[k] = deg[t*8 + k]; s += loc[k]; }
    int x = s;   // inclusive scan within wave
    for (int o = 1; o < 64; o <<= 1) {
        int u = __shfl_up(x, o, 64);
        if (lane >= o) x += u;
    }
    if (lane == 63) wsum[wave] = x;
    __syncthreads();
    int off = 0;
    #pragma unroll
    for (int w = 0; w < 4; w++) if (w < wave) off += wsum[w];
    int base = off + x - s;   // exclusive prefix for this thread
    #pragma unroll
    for (int k = 0; k < 8; k++) {
        csr_off[t*8 + k] = base;
        csr_pos[t*8 + k] = base;
        base += loc[k];
    }
    if (t == 255) csr_off[NN] = off + x;
}

__global__ void k_fill(const int* __restrict__ dst, int* __restrict__ csr_pos,
                       int* __restrict__ csr_e) {
    int e = blockIdx.x * 256 + threadIdx.x;
    if (e < NET) {
        int d = (e < NE) ? dst[e] : (e - NE);
        int pos = atomicAdd(&csr_pos[d], 1);
        csr_e[pos] = e;
    }
}

// ---------------------------------------------------------------------------
// K4: per-edge dot-attention denominator only. One WAVE per edge, 4 edges
//     per block. Coalesced 1KB wave-loads, shuffle reduce, no LDS/barrier.
//     datt[e] = 1 / (slog[s].slog[d] + 1)
// ---------------------------------------------------------------------------
__global__ __launch_bounds__(256) void k_datt(
    const int* __restrict__ src, const int* __restrict__ dst,
    const float* __restrict__ slog, float* __restrict__ datt) {
    const int e = blockIdx.x * 4 + (threadIdx.x >> 6);   // NET = 4608*4 exactly
    const int lane = threadIdx.x & 63;
    int s, d;
    if (e < NE) { s = src[e]; d = dst[e]; } else { s = d = e - NE; }
    const float4* A = (const float4*)(slog + (size_t)s * NN);
    const float4* B = (const float4*)(slog + (size_t)d * NN);
    float p = 0.0f;
    #pragma unroll
    for (int i = 0; i < 8; i++) {
        float4 a = A[lane + 64 * i];
        float4 b = B[lane + 64 * i];
        p = fmaf(a.x, b.x, p); p = fmaf(a.y, b.y, p);
        p = fmaf(a.z, b.z, p); p = fmaf(a.w, b.w, p);
    }
    #pragma unroll
    for (int o = 32; o; o >>= 1) p += __shfl_down(p, o);
    if (lane == 0) datt[e] = 1.0f / (p + 1.0f);
}

// ---------------------------------------------------------------------------
// K5: fused per-destination segment softmax + BOTH aggregations.
//     alpha computed inline: lrelu(sa[s]+ra[d]) * datt[e]; softmax per head;
//     single loop aggregates xh rows (float2, coalesced) and onehot rows
//     (2x float4) -> out_x (+bias) and out_oh (+own row).
// ---------------------------------------------------------------------------
__global__ __launch_bounds__(256) void k_agg(
    const int* __restrict__ src, const int* __restrict__ csr_off,
    const int* __restrict__ csr_e, const float* __restrict__ datt,
    const float* __restrict__ sa, const float* __restrict__ ra,
    const float* __restrict__ xh, const float* __restrict__ onehot,
    const float* __restrict__ bias, float* __restrict__ out_x,
    float* __restrict__ out_oh) {
    const int d = blockIdx.x;
    const int begin = csr_off[d];
    int deg = csr_off[d + 1] - begin;
    if (deg > CAP) deg = CAP;   // unreachable for this input distribution
    __shared__ float wls[CAP * 4];
    __shared__ int   sls[CAP];
    const int tid = threadIdx.x;
    const float4 rav = *(const float4*)(ra + d * 4);
    for (int t = tid; t < deg; t += 256) {
        int e = csr_e[begin + t];
        int s = (e < NE) ? src[e] : (e - NE);
        sls[t] = s;
        float4 sav = *(const float4*)(sa + s * 4);
        float dt = datt[e];
        float a0 = sav.x + rav.x; a0 = (a0 >= 0.0f ? a0 : NEG_SLOPE * a0) * dt;
        float a1 = sav.y + rav.y; a1 = (a1 >= 0.0f ? a1 : NEG_SLOPE * a1) * dt;
        float a2 = sav.z + rav.z; a2 = (a2 >= 0.0f ? a2 : NEG_SLOPE * a2) * dt;
        float a3 = sav.w + rav.w; a3 = (a3 >= 0.0f ? a3 : NEG_SLOPE * a3) * dt;
        wls[t*4 + 0] = a0; wls[t*4 + 1] = a1;
        wls[t*4 + 2] = a2; wls[t*4 + 3] = a3;
    }
    __syncthreads();
    const int wave = tid >> 6, lane = tid & 63;
    {   // wave w owns head w (4 waves exactly)
        float m = -3.4e38f;
        for (int t = lane; t < deg; t += 64) m = fmaxf(m, wls[t*4 + wave]);
        for (int o = 32; o; o >>= 1) m = fmaxf(m, __shfl_down(m, o));
        m = __shfl(m, 0);
        float s = 0.0f;
        for (int t = lane; t < deg; t += 64) {
            float ex = expf(wls[t*4 + wave] - m);
            wls[t*4 + wave] = ex;
            s += ex;
        }
        for (int o = 32; o; o >>= 1) s += __shfl_down(s, o);
        s = __shfl(s, 0);
        float inv = 1.0f / (s + 1e-16f);
        for (int t = lane; t < deg; t += 64) wls[t*4 + wave] *= inv;
    }
    __syncthreads();
    // ---- single aggregation loop: xh (float2/thread) + onehot (2x float4) ----
    const int h = tid >> 6;          // head of output pair ho = 2*tid, 2*tid+1
    float2 accx; accx.x = 0.0f; accx.y = 0.0f;
    const float4* own = (const float4*)(onehot + (size_t)d * NN);
    float4 A = own[tid], B = own[tid + 256];
    const float2* xh2 = (const float2*)xh;
    const float4* oh4 = (const float4*)onehot;
    for (int t = 0; t < deg; t++) {
        const float w = wls[t*4 + h];
        const int s = sls[t];
        float2 xv = xh2[(size_t)s * 256 + tid];
        accx.x = fmaf(w, xv.x, accx.x);
        accx.y = fmaf(w, xv.y, accx.y);
        float4 u  = oh4[(size_t)s * 512 + tid];
        float4 vv = oh4[(size_t)s * 512 + 256 + tid];
        A.x += u.x;  A.y += u.y;  A.z += u.z;  A.w += u.w;
        B.x += vv.x; B.y += vv.y; B.z += vv.z; B.w += vv.w;
    }
    float2 bv = ((const float2*)bias)[tid];
    float2 outv; outv.x = accx.x + bv.x; outv.y = accx.y + bv.y;
    ((float2*)out_x)[(size_t)d * 256 + tid] = outv;
    float4* o4 = (float4*)(out_oh + (size_t)d * NN);
    o4[tid] = A; o4[tid + 256] = B;
}

// ---------------------------------------------------------------------------
extern "C" void kernel_launch(void* const* d_in, const int* in_sizes, int n_in,
                              void* d_out, int out_size, void* d_ws, size_t ws_size,
                              hipStream_t stream) {
    const float* x      = (const float*)d_in[0];
    const float* onehot = (const float*)d_in[1];
    const int*   src    = (const int*)d_in[2];
    const int*   dst    = (const int*)d_in[3];
    const float* lin_w  = (const float*)d_in[4];
    const float* att_l  = (const float*)d_in[5];
    const float* att_r  = (const float*)d_in[6];
    const float* bias   = (const float*)d_in[7];
    const float* c1w    = (const float*)d_in[8];
    const float* c1b    = (const float*)d_in[9];
    const float* c2w    = (const float*)d_in[10];
    const float* c2b    = (const float*)d_in[11];
    const float* fcw    = (const float*)d_in[12];
    const float* fcb    = (const float*)d_in[13];

    float* out_x  = (float*)d_out;                       // [N, 512]
    float* out_oh = out_x + (size_t)NN * (NH * OUTF);    // [N, N]

    // Workspace layout (~21 MB)
    float* ws    = (float*)d_ws;
    float* slog  = ws;                           // N*N
    float* xh    = slog + (size_t)NN * NN;       // N*512
    float* ohf   = xh   + (size_t)NN * 512;      // N*8
    float* sa    = ohf  + (size_t)NN * OHF;      // N*4
    float* ra    = sa   + (size_t)NN * NH;       // N*4
    float* datt  = ra   + (size_t)NN * NH;       // NET
    int* deg     = (int*)(datt + (size_t)NET);
    int* csr_off = deg + NN;                     // N+1
    int* csr_pos = csr_off + NN + 1;             // N
    int* csr_e   = csr_pos + NN;                 // NET

    hipMemsetAsync(deg, 0, NN * sizeof(int), stream);
    k_sortconv<<<NN, 256, 0, stream>>>(onehot, c1w, c1b, c2w, c2b, fcw, fcb, slog, ohf);
    k_count<<<(NET + 255) / 256, 256, 0, stream>>>(dst, deg);
    k_scan<<<1, 256, 0, stream>>>(deg, csr_off, csr_pos);
    k_fill<<<(NET + 255) / 256, 256, 0, stream>>>(dst, csr_pos, csr_e);
    k_xh<<<NN / 4, 256, 0, stream>>>(x, ohf, lin_w, att_l, att_r, xh, sa, ra);
    k_datt<<<NET / 4, 256, 0, stream>>>(src, dst, slog, datt);
    k_agg<<<NN, 256, 0, stream>>>(src, csr_off, csr_e, datt, sa, ra, xh, onehot,
                                  bias, out_x, out_oh);
}

// Round 12
// 286.151 us; speedup vs baseline: 1.0438x; 1.0206x over previous
//
#include <hip/hip_runtime.h>
#include <math.h>

// Problem constants (match reference)
#define NN   2048
#define NE   16384
#define NET  (NE + NN)   // 18432 edges incl. self loops
#define INF_ 128
#define OUTF 128
#define NH   4
#define OHF  8
#define NEG_SLOPE 0.2f
#define CAP  512         // max in-degree supported (actual max ~25 for this seed)

// fast symlog: |err| ~3e-7, fine vs harness tolerance
__device__ __forceinline__ float symlogf_(float v) {
    return copysignf(__logf(1.0f + fabsf(v)), v);
}

// ---------------------------------------------------------------------------
// K1: per-row sort (hybrid register/shuffle/LDS bitonic) + symlog +
//     conv1(1->8,k3,p1)+relu + conv2(8->16,k3,p1)+relu + mean-pool + fc(16->8).
//     Also writes slog = symlog(onehot) (unsorted) and the SELF-LOOP dot-att
//     denominator datt[NE+r] = 1/(||symlog row||^2 + 1)  (sum of squares is
//     permutation-invariant, so the sorted registers suffice).
// ---------------------------------------------------------------------------
__global__ __launch_bounds__(256, 4) void k_sortconv(
    const float* __restrict__ onehot,
    const float* __restrict__ c1w, const float* __restrict__ c1b,
    const float* __restrict__ c2w, const float* __restrict__ c2b,
    const float* __restrict__ fcw, const float* __restrict__ fcb,
    float* __restrict__ slog, float* __restrict__ ohfeat,
    float* __restrict__ datt) {
    __shared__ float soa[NN];         // SoA exchange buffer: soa[e*256 + t]
    __shared__ float bndL[4][2];      // wave-boundary passing (v6,v7 of lane63)
    __shared__ float bndR[4][2];      // (v0,v1 of lane0)
    __shared__ float red[64];
    __shared__ float red2[4];
    __shared__ float pooled[16];
    const int t = threadIdx.x;
    const int r = blockIdx.x;
    const int b = t << 3;             // base element index of this thread
    const int wave = t >> 6, lane = t & 63;
    const float* row  = onehot + (size_t)r * NN;
    float*       srow = slog   + (size_t)r * NN;

    // ---- load 8 elements into registers; write symlog(unsorted) out ----
    float4 lo = ((const float4*)row)[t * 2];
    float4 hi = ((const float4*)row)[t * 2 + 1];
    float v[8] = {lo.x, lo.y, lo.z, lo.w, hi.x, hi.y, hi.z, hi.w};
    {
        float4 s0, s1;
        s0.x = symlogf_(v[0]); s0.y = symlogf_(v[1]);
        s0.z = symlogf_(v[2]); s0.w = symlogf_(v[3]);
        s1.x = symlogf_(v[4]); s1.y = symlogf_(v[5]);
        s1.z = symlogf_(v[6]); s1.w = symlogf_(v[7]);
        ((float4*)srow)[t * 2]     = s0;
        ((float4*)srow)[t * 2 + 1] = s1;
    }

    // compare-exchange: if up, x=min,y=max; else x=max,y=min
    auto cx = [](float& x, float& y, bool up) {
        float mn = fminf(x, y), mx = fmaxf(x, y);
        x = up ? mn : mx;
        y = up ? mx : mn;
    };

    // ---- in-register phases k=2,4,8 ----
    cx(v[0], v[1], true);  cx(v[2], v[3], false);
    cx(v[4], v[5], true);  cx(v[6], v[7], false);
    cx(v[0], v[2], true);  cx(v[1], v[3], true);
    cx(v[4], v[6], false); cx(v[5], v[7], false);
    cx(v[0], v[1], true);  cx(v[2], v[3], true);
    cx(v[4], v[5], false); cx(v[6], v[7], false);
    {
        const bool u8 = ((t & 1) == 0);
        cx(v[0], v[4], u8); cx(v[1], v[5], u8); cx(v[2], v[6], u8); cx(v[3], v[7], u8);
        cx(v[0], v[2], u8); cx(v[1], v[3], u8); cx(v[4], v[6], u8); cx(v[5], v[7], u8);
        cx(v[0], v[1], u8); cx(v[2], v[3], u8); cx(v[4], v[5], u8); cx(v[6], v[7], u8);
    }

    // ---- phases k=16..2048 ----
    for (int k = 16; k <= NN; k <<= 1) {
        const bool up = ((b & k) == 0);           // uniform per thread
        for (int j = k >> 1; j >= 8; j >>= 1) {
            const int pj = j >> 3;                // partner distance in threads
            const bool keepmin = (((t & pj) == 0) == up);
            if (pj <= 32) {
                #pragma unroll
                for (int e = 0; e < 8; e++) {
                    float p = __shfl_xor(v[e], pj, 64);
                    v[e] = keepmin ? fminf(v[e], p) : fmaxf(v[e], p);
                }
            } else {
                // cross-wave exchange via conflict-free SoA LDS (3 rounds total)
                __syncthreads();
                #pragma unroll
                for (int e = 0; e < 8; e++) soa[e * 256 + t] = v[e];
                __syncthreads();
                const int pt = t ^ pj;
                #pragma unroll
                for (int e = 0; e < 8; e++) {
                    float p = soa[e * 256 + pt];
                    v[e] = keepmin ? fminf(v[e], p) : fmaxf(v[e], p);
                }
            }
        }
        cx(v[0], v[4], up); cx(v[1], v[5], up); cx(v[2], v[6], up); cx(v[3], v[7], up);
        cx(v[0], v[2], up); cx(v[1], v[3], up); cx(v[4], v[6], up); cx(v[5], v[7], up);
        cx(v[0], v[1], up); cx(v[2], v[3], up); cx(v[4], v[5], up); cx(v[6], v[7], up);
    }

    // ---- symlog of sorted values (monotone => commutes with sort) ----
    #pragma unroll
    for (int e = 0; e < 8; e++) v[e] = symlogf_(v[e]);

    // ---- self-loop dot-att denominator: sum of squares (perm-invariant) ----
    float ssq = 0.0f;
    #pragma unroll
    for (int e = 0; e < 8; e++) ssq = fmaf(v[e], v[e], ssq);

    // ---- neighbor values via shuffles + wave-boundary LDS ----
    __syncthreads();   // soa no longer needed; reuse barriers for bnd
    if (lane == 63) { bndL[wave][0] = v[6]; bndL[wave][1] = v[7]; }
    if (lane == 0)  { bndR[wave][0] = v[0]; bndR[wave][1] = v[1]; }
    __syncthreads();
    float vm2 = __shfl_up(v[6], 1, 64);
    float vm1 = __shfl_up(v[7], 1, 64);
    float vp8 = __shfl_down(v[0], 1, 64);
    float vp9 = __shfl_down(v[1], 1, 64);
    if (lane == 0) {
        vm2 = wave ? bndL[wave - 1][0] : 0.0f;
        vm1 = wave ? bndL[wave - 1][1] : 0.0f;
    }
    if (lane == 63) {
        vp8 = (wave < 3) ? bndR[wave + 1][0] : 0.0f;
        vp9 = (wave < 3) ? bndR[wave + 1][1] : 0.0f;
    }

    // vin[m] = sorted symlog value at position b-2+m (0 outside range)
    float vin[12];
    vin[0] = vm2; vin[1] = vm1;
    #pragma unroll
    for (int e = 0; e < 8; e++) vin[2 + e] = v[e];
    vin[10] = vp8; vin[11] = vp9;

    // ---- conv1: all 10 columns into VGPRs (static indices only) ----
    float h1c[10][8];
    {
        float w1[24], b1[8];
        #pragma unroll
        for (int q = 0; q < 24; q++) w1[q] = c1w[q];
        #pragma unroll
        for (int q = 0; q < 8; q++)  b1[q] = c1b[q];
        #pragma unroll
        for (int m = 0; m < 10; m++) {
            const float xm = vin[m], xc = vin[m + 1], xp = vin[m + 2];
            #pragma unroll
            for (int c = 0; c < 8; c++) {
                float a = fmaf(w1[c * 3 + 2], xp,
                          fmaf(w1[c * 3 + 1], xc,
                          fmaf(w1[c * 3 + 0], xm, b1[c])));
                h1c[m][c] = fmaxf(a, 0.0f);
            }
        }
        if (t == 0) {      // position q=-1 (zero pad)
            #pragma unroll
            for (int c = 0; c < 8; c++) h1c[0][c] = 0.0f;
        }
        if (t == 255) {    // position q=2048 (zero pad)
            #pragma unroll
            for (int c = 0; c < 8; c++) h1c[9][c] = 0.0f;
        }
    }

    // ---- conv2, weight-stationary: ch outer, 24 weights reused 8x ----
    float sums[16];
    #pragma unroll
    for (int ch = 0; ch < 16; ch++) {
        float wch[24];
        #pragma unroll
        for (int q = 0; q < 24; q++) wch[q] = c2w[ch * 24 + q];
        const float bb = c2b[ch];
        float acc = 0.0f;
        #pragma unroll
        for (int i = 0; i < 8; i++) {
            float a = bb;
            #pragma unroll
            for (int c = 0; c < 8; c++) {
                a = fmaf(wch[c * 3 + 0], h1c[i][c],     a);
                a = fmaf(wch[c * 3 + 1], h1c[i + 1][c], a);
                a = fmaf(wch[c * 3 + 2], h1c[i + 2][c], a);
            }
            acc += fmaxf(a, 0.0f);
        }
        sums[ch] = acc;
    }

    // ---- block reduction of 16 channel sums + ssq ----
    #pragma unroll
    for (int c = 0; c < 16; c++)
        for (int o = 32; o; o >>= 1) sums[c] += __shfl_down(sums[c], o);
    #pragma unroll
    for (int o = 32; o; o >>= 1) ssq += __shfl_down(ssq, o);
    if (lane == 0) {
        #pragma unroll
        for (int c = 0; c < 16; c++) red[wave * 16 + c] = sums[c];
        red2[wave] = ssq;
    }
    __syncthreads();
    if (t < 16)
        pooled[t] = (red[t] + red[16 + t] + red[32 + t] + red[48 + t]) * (1.0f / NN);
    if (t == 16)
        datt[NE + r] = 1.0f / (red2[0] + red2[1] + red2[2] + red2[3] + 1.0f);
    __syncthreads();
    if (t < OHF) {
        float a = fcb[t];
        #pragma unroll
        for (int c = 0; c < 16; c++) a = fmaf(fcw[t * 16 + c], pooled[c], a);
        ohfeat[r * OHF + t] = a;
    }
}

// ---------------------------------------------------------------------------
// K2: xh = concat([x, oh_feat]) @ lin_w.T -> [N,512], fused with sa/ra
//     attention logits. UNCHANGED.
// ---------------------------------------------------------------------------
__global__ __launch_bounds__(256) void k_xh(
    const float* __restrict__ x, const float* __restrict__ ohf,
    const float* __restrict__ lin_w, const float* __restrict__ att_l,
    const float* __restrict__ att_r, float* __restrict__ xh,
    float* __restrict__ sa, float* __restrict__ ra) {
    const int n0 = blockIdx.x * 4;
    __shared__ float xin[4][136];
    __shared__ float part[4][16];   // [wave][n*4 + g*2 + lr]
    const int tid = threadIdx.x;
    const int wave = tid >> 6, lane = tid & 63;
    for (int i = tid; i < 4 * 136; i += 256) {
        int nn = i / 136, k = i - nn * 136;
        xin[nn][k] = (k < INF_) ? x[(size_t)(n0+nn)*INF_ + k]
                                : ohf[(n0+nn)*OHF + (k - INF_)];
    }
    __syncthreads();
    float accl[2][4], accr[2][4];
    #pragma unroll
    for (int g = 0; g < 2; g++)
        #pragma unroll
        for (int n = 0; n < 4; n++) { accl[g][n] = 0.0f; accr[g][n] = 0.0f; }

    #pragma unroll
    for (int g = 0; g < 2; g++) {
        const int o = tid + g * 256;
        const float4* wr4 = (const float4*)(lin_w + (size_t)o * 136);
        float a0 = 0, a1 = 0, a2 = 0, a3 = 0;
        for (int kk = 0; kk < 34; kk++) {
            float4 w = wr4[kk];
            int k = kk * 4;
            a0 += w.x*xin[0][k] + w.y*xin[0][k+1] + w.z*xin[0][k+2] + w.w*xin[0][k+3];
            a1 += w.x*xin[1][k] + w.y*xin[1][k+1] + w.z*xin[1][k+2] + w.w*xin[1][k+3];
            a2 += w.x*xin[2][k] + w.y*xin[2][k+1] + w.z*xin[2][k+2] + w.w*xin[2][k+3];
            a3 += w.x*xin[3][k] + w.y*xin[3][k+1] + w.z*xin[3][k+2] + w.w*xin[3][k+3];
        }
        xh[(size_t)(n0+0)*512 + o] = a0;
        xh[(size_t)(n0+1)*512 + o] = a1;
        xh[(size_t)(n0+2)*512 + o] = a2;
        xh[(size_t)(n0+3)*512 + o] = a3;
        const float al = att_l[o], ar = att_r[o];
        accl[g][0] = fmaf(a0, al, accl[g][0]); accr[g][0] = fmaf(a0, ar, accr[g][0]);
        accl[g][1] = fmaf(a1, al, accl[g][1]); accr[g][1] = fmaf(a1, ar, accr[g][1]);
        accl[g][2] = fmaf(a2, al, accl[g][2]); accr[g][2] = fmaf(a2, ar, accr[g][2]);
        accl[g][3] = fmaf(a3, al, accl[g][3]); accr[g][3] = fmaf(a3, ar, accr[g][3]);
    }
    // wave-reduce the 16 accumulators (all lanes of a wave share the same head)
    #pragma unroll
    for (int g = 0; g < 2; g++)
        #pragma unroll
        for (int n = 0; n < 4; n++)
            for (int o = 32; o; o >>= 1) {
                accl[g][n] += __shfl_down(accl[g][n], o);
                accr[g][n] += __shfl_down(accr[g][n], o);
            }
    if (lane == 0) {
        #pragma unroll
        for (int g = 0; g < 2; g++)
            #pragma unroll
            for (int n = 0; n < 4; n++) {
                part[wave][n * 4 + g * 2 + 0] = accl[g][n];
                part[wave][n * 4 + g * 2 + 1] = accr[g][n];
            }
    }
    __syncthreads();
    if (tid < 32) {
        const int n = tid >> 3, rem = tid & 7, h = rem >> 1, lr = rem & 1;
        const int g = h >> 1, wp = (h & 1) * 2;
        const float val = part[wp][n * 4 + g * 2 + lr] + part[wp + 1][n * 4 + g * 2 + lr];
        if (lr == 0) sa[(n0 + n) * 4 + h] = val;
        else         ra[(n0 + n) * 4 + h] = val;
    }
}

// ---------------------------------------------------------------------------
// K3: single-kernel CSR build (one block, LDS counters + scan + atomic fill).
//     Replaces memset + count + scan + fill (4 dispatches -> 1).
// ---------------------------------------------------------------------------
__global__ __launch_bounds__(1024) void k_csr(
    const int* __restrict__ dst, int* __restrict__ csr_off,
    int* __restrict__ csr_e) {
    __shared__ int cnt[NN];
    __shared__ int wtot[16];
    const int t = threadIdx.x;
    const int wave = t >> 6, lane = t & 63;
    for (int i = t; i < NN; i += 1024) cnt[i] = 0;
    __syncthreads();
    for (int e = t; e < NET; e += 1024) {
        int d = (e < NE) ? dst[e] : (e - NE);
        atomicAdd(&cnt[d], 1);
    }
    __syncthreads();
    // scan of 2048 counts: thread t owns cnt[2t], cnt[2t+1]
    int c0 = cnt[2 * t], c1 = cnt[2 * t + 1];
    int s = c0 + c1;
    int x = s;
    for (int o = 1; o < 64; o <<= 1) {
        int u = __shfl_up(x, o, 64);
        if (lane >= o) x += u;
    }
    if (lane == 63) wtot[wave] = x;
    __syncthreads();
    int off = 0;
    #pragma unroll
    for (int w = 0; w < 16; w++) if (w < wave) off += wtot[w];
    const int base = off + x - s;   // exclusive prefix of this thread's pair
    csr_off[2 * t]     = base;
    csr_off[2 * t + 1] = base + c0;
    if (t == 1023) csr_off[NN] = off + x;
    __syncthreads();
    cnt[2 * t]     = base;          // reuse cnt[] as running positions
    cnt[2 * t + 1] = base + c0;
    __syncthreads();
    for (int e = t; e < NET; e += 1024) {
        int d = (e < NE) ? dst[e] : (e - NE);
        int p = atomicAdd(&cnt[d], 1);
        csr_e[p] = e;
    }
}

// ---------------------------------------------------------------------------
// K4: per-edge dot-attention denominator (REAL edges only; self-loops were
//     produced by k_sortconv). One wave per edge, 4 edges per block.
// ---------------------------------------------------------------------------
__global__ __launch_bounds__(256) void k_datt(
    const int* __restrict__ src, const int* __restrict__ dst,
    const float* __restrict__ slog, float* __restrict__ datt) {
    const int e = blockIdx.x * 4 + (threadIdx.x >> 6);   // NE = 4096*4 exactly
    const int lane = threadIdx.x & 63;
    const int s = src[e], d = dst[e];
    const float4* A = (const float4*)(slog + (size_t)s * NN);
    const float4* B = (const float4*)(slog + (size_t)d * NN);
    float p = 0.0f;
    #pragma unroll
    for (int i = 0; i < 8; i++) {
        float4 a = A[lane + 64 * i];
        float4 b = B[lane + 64 * i];
        p = fmaf(a.x, b.x, p); p = fmaf(a.y, b.y, p);
        p = fmaf(a.z, b.z, p); p = fmaf(a.w, b.w, p);
    }
    #pragma unroll
    for (int o = 32; o; o >>= 1) p += __shfl_down(p, o);
    if (lane == 0) datt[e] = 1.0f / (p + 1.0f);
}

// ---------------------------------------------------------------------------
// K5: fused per-destination segment softmax + BOTH aggregations. UNCHANGED.
// ---------------------------------------------------------------------------
__global__ __launch_bounds__(256) void k_agg(
    const int* __restrict__ src, const int* __restrict__ csr_off,
    const int* __restrict__ csr_e, const float* __restrict__ datt,
    const float* __restrict__ sa, const float* __restrict__ ra,
    const float* __restrict__ xh, const float* __restrict__ onehot,
    const float* __restrict__ bias, float* __restrict__ out_x,
    float* __restrict__ out_oh) {
    const int d = blockIdx.x;
    const int begin = csr_off[d];
    int deg = csr_off[d + 1] - begin;
    if (deg > CAP) deg = CAP;   // unreachable for this input distribution
    __shared__ float wls[CAP * 4];
    __shared__ int   sls[CAP];
    const int tid = threadIdx.x;
    const float4 rav = *(const float4*)(ra + d * 4);
    for (int t = tid; t < deg; t += 256) {
        int e = csr_e[begin + t];
        int s = (e < NE) ? src[e] : (e - NE);
        sls[t] = s;
        float4 sav = *(const float4*)(sa + s * 4);
        float dt = datt[e];
        float a0 = sav.x + rav.x; a0 = (a0 >= 0.0f ? a0 : NEG_SLOPE * a0) * dt;
        float a1 = sav.y + rav.y; a1 = (a1 >= 0.0f ? a1 : NEG_SLOPE * a1) * dt;
        float a2 = sav.z + rav.z; a2 = (a2 >= 0.0f ? a2 : NEG_SLOPE * a2) * dt;
        float a3 = sav.w + rav.w; a3 = (a3 >= 0.0f ? a3 : NEG_SLOPE * a3) * dt;
        wls[t*4 + 0] = a0; wls[t*4 + 1] = a1;
        wls[t*4 + 2] = a2; wls[t*4 + 3] = a3;
    }
    __syncthreads();
    const int wave = tid >> 6, lane = tid & 63;
    {   // wave w owns head w (4 waves exactly)
        float m = -3.4e38f;
        for (int t = lane; t < deg; t += 64) m = fmaxf(m, wls[t*4 + wave]);
        for (int o = 32; o; o >>= 1) m = fmaxf(m, __shfl_down(m, o));
        m = __shfl(m, 0);
        float s = 0.0f;
        for (int t = lane; t < deg; t += 64) {
            float ex = expf(wls[t*4 + wave] - m);
            wls[t*4 + wave] = ex;
            s += ex;
        }
        for (int o = 32; o; o >>= 1) s += __shfl_down(s, o);
        s = __shfl(s, 0);
        float inv = 1.0f / (s + 1e-16f);
        for (int t = lane; t < deg; t += 64) wls[t*4 + wave] *= inv;
    }
    __syncthreads();
    // ---- single aggregation loop: xh (float2/thread) + onehot (2x float4) ----
    const int h = tid >> 6;          // head of output pair ho = 2*tid, 2*tid+1
    float2 accx; accx.x = 0.0f; accx.y = 0.0f;
    const float4* own = (const float4*)(onehot + (size_t)d * NN);
    float4 A = own[tid], B = own[tid + 256];
    const float2* xh2 = (const float2*)xh;
    const float4* oh4 = (const float4*)onehot;
    for (int t = 0; t < deg; t++) {
        const float w = wls[t*4 + h];
        const int s = sls[t];
        float2 xv = xh2[(size_t)s * 256 + tid];
        accx.x = fmaf(w, xv.x, accx.x);
        accx.y = fmaf(w, xv.y, accx.y);
        float4 u  = oh4[(size_t)s * 512 + tid];
        float4 vv = oh4[(size_t)s * 512 + 256 + tid];
        A.x += u.x;  A.y += u.y;  A.z += u.z;  A.w += u.w;
        B.x += vv.x; B.y += vv.y; B.z += vv.z; B.w += vv.w;
    }
    float2 bv = ((const float2*)bias)[tid];
    float2 outv; outv.x = accx.x + bv.x; outv.y = accx.y + bv.y;
    ((float2*)out_x)[(size_t)d * 256 + tid] = outv;
    float4* o4 = (float4*)(out_oh + (size_t)d * NN);
    o4[tid] = A; o4[tid + 256] = B;
}

// ---------------------------------------------------------------------------
extern "C" void kernel_launch(void* const* d_in, const int* in_sizes, int n_in,
                              void* d_out, int out_size, void* d_ws, size_t ws_size,
                              hipStream_t stream) {
    const float* x      = (const float*)d_in[0];
    const float* onehot = (const float*)d_in[1];
    const int*   src    = (const int*)d_in[2];
    const int*   dst    = (const int*)d_in[3];
    const float* lin_w  = (const float*)d_in[4];
    const float* att_l  = (const float*)d_in[5];
    const float* att_r  = (const float*)d_in[6];
    const float* bias   = (const float*)d_in[7];
    const float* c1w    = (const float*)d_in[8];
    const float* c1b    = (const float*)d_in[9];
    const float* c2w    = (const float*)d_in[10];
    const float* c2b    = (const float*)d_in[11];
    const float* fcw    = (const float*)d_in[12];
    const float* fcb    = (const float*)d_in[13];

    float* out_x  = (float*)d_out;                       // [N, 512]
    float* out_oh = out_x + (size_t)NN * (NH * OUTF);    // [N, N]

    // Workspace layout (~21 MB)
    float* ws    = (float*)d_ws;
    float* slog  = ws;                           // N*N
    float* xh    = slog + (size_t)NN * NN;       // N*512
    float* ohf   = xh   + (size_t)NN * 512;      // N*8
    float* sa    = ohf  + (size_t)NN * OHF;      // N*4
    float* ra    = sa   + (size_t)NN * NH;       // N*4
    float* datt  = ra   + (size_t)NN * NH;       // NET
    int* csr_off = (int*)(datt + (size_t)NET);   // N+1
    int* csr_e   = csr_off + NN + 1;             // NET

    k_sortconv<<<NN, 256, 0, stream>>>(onehot, c1w, c1b, c2w, c2b, fcw, fcb,
                                       slog, ohf, datt);
    k_csr<<<1, 1024, 0, stream>>>(dst, csr_off, csr_e);
    k_xh<<<NN / 4, 256, 0, stream>>>(x, ohf, lin_w, att_l, att_r, xh, sa, ra);
    k_datt<<<NE / 4, 256, 0, stream>>>(src, dst, slog, datt);
    k_agg<<<NN, 256, 0, stream>>>(src, csr_off, csr_e, datt, sa, ra, xh, onehot,
                                  bias, out_x, out_oh);
}

// Round 15
// 260.122 us; speedup vs baseline: 1.1482x; 1.1001x over previous
//
#include <hip/hip_runtime.h>
#include <math.h>

// Problem constants (match reference)
#define NN   2048
#define NE   16384
#define NET  (NE + NN)   // 18432 edges incl. self loops
#define INF_ 128
#define OUTF 128
#define NH   4
#define OHF  8
#define NEG_SLOPE 0.2f
#define CAP  512         // max in-degree supported (actual max ~25 for this seed)

// fast symlog: |err| ~3e-7, fine vs harness tolerance
__device__ __forceinline__ float symlogf_(float v) {
    return copysignf(__logf(1.0f + fabsf(v)), v);
}

// ---------------------------------------------------------------------------
// K1: per-row sort (hybrid register/shuffle/LDS bitonic) + symlog +
//     conv1(1->8,k3,p1)+relu + conv2(8->16,k3,p1)+relu + mean-pool + fc(16->8).
//     slog/datt outputs REMOVED (consumer computes symlog on the fly now).
// ---------------------------------------------------------------------------
__global__ __launch_bounds__(256, 4) void k_sortconv(
    const float* __restrict__ onehot,
    const float* __restrict__ c1w, const float* __restrict__ c1b,
    const float* __restrict__ c2w, const float* __restrict__ c2b,
    const float* __restrict__ fcw, const float* __restrict__ fcb,
    float* __restrict__ ohfeat) {
    __shared__ float soa[NN];         // SoA exchange buffer: soa[e*256 + t]
    __shared__ float bndL[4][2];      // wave-boundary passing (v6,v7 of lane63)
    __shared__ float bndR[4][2];      // (v0,v1 of lane0)
    __shared__ float red[64];
    __shared__ float pooled[16];
    const int t = threadIdx.x;
    const int r = blockIdx.x;
    const int b = t << 3;             // base element index of this thread
    const int wave = t >> 6, lane = t & 63;
    const float* row = onehot + (size_t)r * NN;

    // ---- load 8 elements into registers ----
    float4 lo = ((const float4*)row)[t * 2];
    float4 hi = ((const float4*)row)[t * 2 + 1];
    float v[8] = {lo.x, lo.y, lo.z, lo.w, hi.x, hi.y, hi.z, hi.w};

    // compare-exchange: if up, x=min,y=max; else x=max,y=min
    auto cx = [](float& x, float& y, bool up) {
        float mn = fminf(x, y), mx = fmaxf(x, y);
        x = up ? mn : mx;
        y = up ? mx : mn;
    };

    // ---- in-register phases k=2,4,8 ----
    cx(v[0], v[1], true);  cx(v[2], v[3], false);
    cx(v[4], v[5], true);  cx(v[6], v[7], false);
    cx(v[0], v[2], true);  cx(v[1], v[3], true);
    cx(v[4], v[6], false); cx(v[5], v[7], false);
    cx(v[0], v[1], true);  cx(v[2], v[3], true);
    cx(v[4], v[5], false); cx(v[6], v[7], false);
    {
        const bool u8 = ((t & 1) == 0);
        cx(v[0], v[4], u8); cx(v[1], v[5], u8); cx(v[2], v[6], u8); cx(v[3], v[7], u8);
        cx(v[0], v[2], u8); cx(v[1], v[3], u8); cx(v[4], v[6], u8); cx(v[5], v[7], u8);
        cx(v[0], v[1], u8); cx(v[2], v[3], u8); cx(v[4], v[5], u8); cx(v[6], v[7], u8);
    }

    // ---- phases k=16..2048 ----
    for (int k = 16; k <= NN; k <<= 1) {
        const bool up = ((b & k) == 0);           // uniform per thread
        for (int j = k >> 1; j >= 8; j >>= 1) {
            const int pj = j >> 3;                // partner distance in threads
            const bool keepmin = (((t & pj) == 0) == up);
            if (pj <= 32) {
                #pragma unroll
                for (int e = 0; e < 8; e++) {
                    float p = __shfl_xor(v[e], pj, 64);
                    v[e] = keepmin ? fminf(v[e], p) : fmaxf(v[e], p);
                }
            } else {
                // cross-wave exchange via conflict-free SoA LDS (3 rounds total)
                __syncthreads();
                #pragma unroll
                for (int e = 0; e < 8; e++) soa[e * 256 + t] = v[e];
                __syncthreads();
                const int pt = t ^ pj;
                #pragma unroll
                for (int e = 0; e < 8; e++) {
                    float p = soa[e * 256 + pt];
                    v[e] = keepmin ? fminf(v[e], p) : fmaxf(v[e], p);
                }
            }
        }
        cx(v[0], v[4], up); cx(v[1], v[5], up); cx(v[2], v[6], up); cx(v[3], v[7], up);
        cx(v[0], v[2], up); cx(v[1], v[3], up); cx(v[4], v[6], up); cx(v[5], v[7], up);
        cx(v[0], v[1], up); cx(v[2], v[3], up); cx(v[4], v[5], up); cx(v[6], v[7], up);
    }

    // ---- symlog of sorted values (monotone => commutes with sort) ----
    #pragma unroll
    for (int e = 0; e < 8; e++) v[e] = symlogf_(v[e]);

    // ---- neighbor values via shuffles + wave-boundary LDS ----
    __syncthreads();   // soa no longer needed; reuse barriers for bnd
    if (lane == 63) { bndL[wave][0] = v[6]; bndL[wave][1] = v[7]; }
    if (lane == 0)  { bndR[wave][0] = v[0]; bndR[wave][1] = v[1]; }
    __syncthreads();
    float vm2 = __shfl_up(v[6], 1, 64);
    float vm1 = __shfl_up(v[7], 1, 64);
    float vp8 = __shfl_down(v[0], 1, 64);
    float vp9 = __shfl_down(v[1], 1, 64);
    if (lane == 0) {
        vm2 = wave ? bndL[wave - 1][0] : 0.0f;
        vm1 = wave ? bndL[wave - 1][1] : 0.0f;
    }
    if (lane == 63) {
        vp8 = (wave < 3) ? bndR[wave + 1][0] : 0.0f;
        vp9 = (wave < 3) ? bndR[wave + 1][1] : 0.0f;
    }

    // vin[m] = sorted symlog value at position b-2+m (0 outside range)
    float vin[12];
    vin[0] = vm2; vin[1] = vm1;
    #pragma unroll
    for (int e = 0; e < 8; e++) vin[2 + e] = v[e];
    vin[10] = vp8; vin[11] = vp9;

    // ---- conv1: all 10 columns into VGPRs (static indices only) ----
    float h1c[10][8];
    {
        float w1[24], b1[8];
        #pragma unroll
        for (int q = 0; q < 24; q++) w1[q] = c1w[q];
        #pragma unroll
        for (int q = 0; q < 8; q++)  b1[q] = c1b[q];
        #pragma unroll
        for (int m = 0; m < 10; m++) {
            const float xm = vin[m], xc = vin[m + 1], xp = vin[m + 2];
            #pragma unroll
            for (int c = 0; c < 8; c++) {
                float a = fmaf(w1[c * 3 + 2], xp,
                          fmaf(w1[c * 3 + 1], xc,
                          fmaf(w1[c * 3 + 0], xm, b1[c])));
                h1c[m][c] = fmaxf(a, 0.0f);
            }
        }
        if (t == 0) {      // position q=-1 (zero pad)
            #pragma unroll
            for (int c = 0; c < 8; c++) h1c[0][c] = 0.0f;
        }
        if (t == 255) {    // position q=2048 (zero pad)
            #pragma unroll
            for (int c = 0; c < 8; c++) h1c[9][c] = 0.0f;
        }
    }

    // ---- conv2, weight-stationary: ch outer, 24 weights reused 8x ----
    float sums[16];
    #pragma unroll
    for (int ch = 0; ch < 16; ch++) {
        float wch[24];
        #pragma unroll
        for (int q = 0; q < 24; q++) wch[q] = c2w[ch * 24 + q];
        const float bb = c2b[ch];
        float acc = 0.0f;
        #pragma unroll
        for (int i = 0; i < 8; i++) {
            float a = bb;
            #pragma unroll
            for (int c = 0; c < 8; c++) {
                a = fmaf(wch[c * 3 + 0], h1c[i][c],     a);
                a = fmaf(wch[c * 3 + 1], h1c[i + 1][c], a);
                a = fmaf(wch[c * 3 + 2], h1c[i + 2][c], a);
            }
            acc += fmaxf(a, 0.0f);
        }
        sums[ch] = acc;
    }

    // ---- block reduction of 16 channel sums ----
    #pragma unroll
    for (int c = 0; c < 16; c++)
        for (int o = 32; o; o >>= 1) sums[c] += __shfl_down(sums[c], o);
    if (lane == 0)
        #pragma unroll
        for (int c = 0; c < 16; c++) red[wave * 16 + c] = sums[c];
    __syncthreads();
    if (t < 16)
        pooled[t] = (red[t] + red[16 + t] + red[32 + t] + red[48 + t]) * (1.0f / NN);
    __syncthreads();
    if (t < OHF) {
        float a = fcb[t];
        #pragma unroll
        for (int c = 0; c < 16; c++) a = fmaf(fcw[t * 16 + c], pooled[c], a);
        ohfeat[r * OHF + t] = a;
    }
}

// ---------------------------------------------------------------------------
// K2: xh = concat([x, oh_feat]) @ lin_w.T -> [N,512], fused with sa/ra
//     attention logits. UNCHANGED.
// ---------------------------------------------------------------------------
__global__ __launch_bounds__(256) void k_xh(
    const float* __restrict__ x, const float* __restrict__ ohf,
    const float* __restrict__ lin_w, const float* __restrict__ att_l,
    const float* __restrict__ att_r, float* __restrict__ xh,
    float* __restrict__ sa, float* __restrict__ ra) {
    const int n0 = blockIdx.x * 4;
    __shared__ float xin[4][136];
    __shared__ float part[4][16];   // [wave][n*4 + g*2 + lr]
    const int tid = threadIdx.x;
    const int wave = tid >> 6, lane = tid & 63;
    for (int i = tid; i < 4 * 136; i += 256) {
        int nn = i / 136, k = i - nn * 136;
        xin[nn][k] = (k < INF_) ? x[(size_t)(n0+nn)*INF_ + k]
                                : ohf[(n0+nn)*OHF + (k - INF_)];
    }
    __syncthreads();
    float accl[2][4], accr[2][4];
    #pragma unroll
    for (int g = 0; g < 2; g++)
        #pragma unroll
        for (int n = 0; n < 4; n++) { accl[g][n] = 0.0f; accr[g][n] = 0.0f; }

    #pragma unroll
    for (int g = 0; g < 2; g++) {
        const int o = tid + g * 256;
        const float4* wr4 = (const float4*)(lin_w + (size_t)o * 136);
        float a0 = 0, a1 = 0, a2 = 0, a3 = 0;
        for (int kk = 0; kk < 34; kk++) {
            float4 w = wr4[kk];
            int k = kk * 4;
            a0 += w.x*xin[0][k] + w.y*xin[0][k+1] + w.z*xin[0][k+2] + w.w*xin[0][k+3];
            a1 += w.x*xin[1][k] + w.y*xin[1][k+1] + w.z*xin[1][k+2] + w.w*xin[1][k+3];
            a2 += w.x*xin[2][k] + w.y*xin[2][k+1] + w.z*xin[2][k+2] + w.w*xin[2][k+3];
            a3 += w.x*xin[3][k] + w.y*xin[3][k+1] + w.z*xin[3][k+2] + w.w*xin[3][k+3];
        }
        xh[(size_t)(n0+0)*512 + o] = a0;
        xh[(size_t)(n0+1)*512 + o] = a1;
        xh[(size_t)(n0+2)*512 + o] = a2;
        xh[(size_t)(n0+3)*512 + o] = a3;
        const float al = att_l[o], ar = att_r[o];
        accl[g][0] = fmaf(a0, al, accl[g][0]); accr[g][0] = fmaf(a0, ar, accr[g][0]);
        accl[g][1] = fmaf(a1, al, accl[g][1]); accr[g][1] = fmaf(a1, ar, accr[g][1]);
        accl[g][2] = fmaf(a2, al, accl[g][2]); accr[g][2] = fmaf(a2, ar, accr[g][2]);
        accl[g][3] = fmaf(a3, al, accl[g][3]); accr[g][3] = fmaf(a3, ar, accr[g][3]);
    }
    // wave-reduce the 16 accumulators (all lanes of a wave share the same head)
    #pragma unroll
    for (int g = 0; g < 2; g++)
        #pragma unroll
        for (int n = 0; n < 4; n++)
            for (int o = 32; o; o >>= 1) {
                accl[g][n] += __shfl_down(accl[g][n], o);
                accr[g][n] += __shfl_down(accr[g][n], o);
            }
    if (lane == 0) {
        #pragma unroll
        for (int g = 0; g < 2; g++)
            #pragma unroll
            for (int n = 0; n < 4; n++) {
                part[wave][n * 4 + g * 2 + 0] = accl[g][n];
                part[wave][n * 4 + g * 2 + 1] = accr[g][n];
            }
    }
    __syncthreads();
    if (tid < 32) {
        const int n = tid >> 3, rem = tid & 7, h = rem >> 1, lr = rem & 1;
        const int g = h >> 1, wp = (h & 1) * 2;
        const float val = part[wp][n * 4 + g * 2 + lr] + part[wp + 1][n * 4 + g * 2 + lr];
        if (lr == 0) sa[(n0 + n) * 4 + h] = val;
        else         ra[(n0 + n) * 4 + h] = val;
    }
}

// ---------------------------------------------------------------------------
// K3: single-kernel CSR build (one block, LDS counters + scan + atomic fill).
//     UNCHANGED.
// ---------------------------------------------------------------------------
__global__ __launch_bounds__(1024) void k_csr(
    const int* __restrict__ dst, int* __restrict__ csr_off,
    int* __restrict__ csr_e) {
    __shared__ int cnt[NN];
    __shared__ int wtot[16];
    const int t = threadIdx.x;
    const int wave = t >> 6, lane = t & 63;
    for (int i = t; i < NN; i += 1024) cnt[i] = 0;
    __syncthreads();
    for (int e = t; e < NET; e += 1024) {
        int d = (e < NE) ? dst[e] : (e - NE);
        atomicAdd(&cnt[d], 1);
    }
    __syncthreads();
    // scan of 2048 counts: thread t owns cnt[2t], cnt[2t+1]
    int c0 = cnt[2 * t], c1 = cnt[2 * t + 1];
    int s = c0 + c1;
    int x = s;
    for (int o = 1; o < 64; o <<= 1) {
        int u = __shfl_up(x, o, 64);
        if (lane >= o) x += u;
    }
    if (lane == 63) wtot[wave] = x;
    __syncthreads();
    int off = 0;
    #pragma unroll
    for (int w = 0; w < 16; w++) if (w < wave) off += wtot[w];
    const int base = off + x - s;   // exclusive prefix of this thread's pair
    csr_off[2 * t]     = base;
    csr_off[2 * t + 1] = base + c0;
    if (t == 1023) csr_off[NN] = off + x;
    __syncthreads();
    cnt[2 * t]     = base;          // reuse cnt[] as running positions
    cnt[2 * t + 1] = base + c0;
    __syncthreads();
    for (int e = t; e < NET; e += 1024) {
        int d = (e < NE) ? dst[e] : (e - NE);
        int p = atomicAdd(&cnt[d], 1);
        csr_e[p] = e;
    }
}

// ---------------------------------------------------------------------------
// K4: FULLY FUSED per-destination kernel: single pass over incoming-edge
//     onehot rows computes BOTH the dot-attention denominator (symlog on the
//     fly, dotted against this thread's own-row symlog registers) AND the
//     unweighted onehot aggregation. Then segment softmax, then the weighted
//     xh aggregation. Eliminates k_datt and the 16MB slog array entirely.
// ---------------------------------------------------------------------------
__global__ __launch_bounds__(256) void k_agg(
    const int* __restrict__ src, const int* __restrict__ csr_off,
    const int* __restrict__ csr_e, const float* __restrict__ sa,
    const float* __restrict__ ra, const float* __restrict__ xh,
    const float* __restrict__ onehot, const float* __restrict__ bias,
    float* __restrict__ out_x, float* __restrict__ out_oh) {
    const int d = blockIdx.x;
    const int begin = csr_off[d];
    int deg = csr_off[d + 1] - begin;
    if (deg > CAP) deg = CAP;   // unreachable for this input distribution
    __shared__ float pw[4][CAP];     // per-wave dot partials
    __shared__ float wls[CAP * 4];   // per-edge per-head weights
    __shared__ int   sls[CAP];
    const int tid = threadIdx.x;
    const int wave = tid >> 6, lane = tid & 63;

    // edge list -> LDS (self-loops encoded as s==d; real edges never have s==d)
    for (int t = tid; t < deg; t += 256) {
        int e = csr_e[begin + t];
        sls[t] = (e < NE) ? src[e] : d;
    }

    // own row: thread t owns elements [4t..4t+3] and [1024+4t..1024+4t+3]
    const float4* oh4 = (const float4*)onehot;
    float4 ownA = oh4[(size_t)d * 512 + tid];
    float4 ownB = oh4[(size_t)d * 512 + 256 + tid];
    float4 sA, sB;   // symlog of own elements (stay in registers)
    sA.x = symlogf_(ownA.x); sA.y = symlogf_(ownA.y);
    sA.z = symlogf_(ownA.z); sA.w = symlogf_(ownA.w);
    sB.x = symlogf_(ownB.x); sB.y = symlogf_(ownB.y);
    sB.z = symlogf_(ownB.z); sB.w = symlogf_(ownB.w);
    // out_oh = onehot[d] + sum over edges (self-loop contributes onehot[d] again)
    float4 A, B;
    A.x = 2.0f*ownA.x; A.y = 2.0f*ownA.y; A.z = 2.0f*ownA.z; A.w = 2.0f*ownA.w;
    B.x = 2.0f*ownB.x; B.y = 2.0f*ownB.y; B.z = 2.0f*ownB.z; B.w = 2.0f*ownB.w;
    __syncthreads();

    // ---- pass 1: one read of each edge row -> dot partial + raw accumulation ----
    for (int t = 0; t < deg; t++) {
        const int s = sls[t];     // uniform across block
        float p;
        if (s == d) {
            // self-loop: dot = ||symlog(own)||^2, no load, no extra accumulation
            p = sA.x*sA.x + sA.y*sA.y + sA.z*sA.z + sA.w*sA.w
              + sB.x*sB.x + sB.y*sB.y + sB.z*sB.z + sB.w*sB.w;
        } else {
            float4 u  = oh4[(size_t)s * 512 + tid];
            float4 vv = oh4[(size_t)s * 512 + 256 + tid];
            A.x += u.x;  A.y += u.y;  A.z += u.z;  A.w += u.w;
            B.x += vv.x; B.y += vv.y; B.z += vv.z; B.w += vv.w;
            p = symlogf_(u.x)*sA.x + symlogf_(u.y)*sA.y
              + symlogf_(u.z)*sA.z + symlogf_(u.w)*sA.w
              + symlogf_(vv.x)*sB.x + symlogf_(vv.y)*sB.y
              + symlogf_(vv.z)*sB.z + symlogf_(vv.w)*sB.w;
        }
        #pragma unroll
        for (int o = 32; o; o >>= 1) p += __shfl_down(p, o);
        if (lane == 0) pw[wave][t] = p;
    }
    __syncthreads();

    // ---- finalize per-edge raw attention weights ----
    const float4 rav = *(const float4*)(ra + d * 4);
    for (int t = tid; t < deg; t += 256) {
        const float dot = pw[0][t] + pw[1][t] + pw[2][t] + pw[3][t];
        const float dt  = 1.0f / (dot + 1.0f);
        const int s = sls[t];
        float4 sav = *(const float4*)(sa + s * 4);
        float a0 = sav.x + rav.x; a0 = (a0 >= 0.0f ? a0 : NEG_SLOPE * a0) * dt;
        float a1 = sav.y + rav.y; a1 = (a1 >= 0.0f ? a1 : NEG_SLOPE * a1) * dt;
        float a2 = sav.z + rav.z; a2 = (a2 >= 0.0f ? a2 : NEG_SLOPE * a2) * dt;
        float a3 = sav.w + rav.w; a3 = (a3 >= 0.0f ? a3 : NEG_SLOPE * a3) * dt;
        wls[t*4 + 0] = a0; wls[t*4 + 1] = a1;
        wls[t*4 + 2] = a2; wls[t*4 + 3] = a3;
    }
    __syncthreads();

    // ---- segment softmax per head (wave w owns head w) ----
    {
        float m = -3.4e38f;
        for (int t = lane; t < deg; t += 64) m = fmaxf(m, wls[t*4 + wave]);
        for (int o = 32; o; o >>= 1) m = fmaxf(m, __shfl_down(m, o));
        m = __shfl(m, 0);
        float s = 0.0f;
        for (int t = lane; t < deg; t += 64) {
            float ex = expf(wls[t*4 + wave] - m);
            wls[t*4 + wave] = ex;
            s += ex;
        }
        for (int o = 32; o; o >>= 1) s += __shfl_down(s, o);
        s = __shfl(s, 0);
        float inv = 1.0f / (s + 1e-16f);
        for (int t = lane; t < deg; t += 64) wls[t*4 + wave] *= inv;
    }
    __syncthreads();

    // ---- pass 2: weighted xh aggregation (float2/thread, coalesced) ----
    const int h = tid >> 6;          // head of output pair ho = 2*tid, 2*tid+1
    float2 accx; accx.x = 0.0f; accx.y = 0.0f;
    const float2* xh2 = (const float2*)xh;
    for (int t = 0; t < deg; t++) {
        const float w = wls[t*4 + h];
        const int s = sls[t];
        float2 xv = xh2[(size_t)s * 256 + tid];
        accx.x = fmaf(w, xv.x, accx.x);
        accx.y = fmaf(w, xv.y, accx.y);
    }
    float2 bv = ((const float2*)bias)[tid];
    float2 outv; outv.x = accx.x + bv.x; outv.y = accx.y + bv.y;
    ((float2*)out_x)[(size_t)d * 256 + tid] = outv;
    float4* o4 = (float4*)(out_oh + (size_t)d * NN);
    o4[tid] = A; o4[tid + 256] = B;
}

// ---------------------------------------------------------------------------
extern "C" void kernel_launch(void* const* d_in, const int* in_sizes, int n_in,
                              void* d_out, int out_size, void* d_ws, size_t ws_size,
                              hipStream_t stream) {
    const float* x      = (const float*)d_in[0];
    const float* onehot = (const float*)d_in[1];
    const int*   src    = (const int*)d_in[2];
    const int*   dst    = (const int*)d_in[3];
    const float* lin_w  = (const float*)d_in[4];
    const float* att_l  = (const float*)d_in[5];
    const float* att_r  = (const float*)d_in[6];
    const float* bias   = (const float*)d_in[7];
    const float* c1w    = (const float*)d_in[8];
    const float* c1b    = (const float*)d_in[9];
    const float* c2w    = (const float*)d_in[10];
    const float* c2b    = (const float*)d_in[11];
    const float* fcw    = (const float*)d_in[12];
    const float* fcb    = (const float*)d_in[13];

    float* out_x  = (float*)d_out;                       // [N, 512]
    float* out_oh = out_x + (size_t)NN * (NH * OUTF);    // [N, N]

    // Workspace layout (~4.4 MB; slog/datt eliminated)
    float* ws    = (float*)d_ws;
    float* xh    = ws;                           // N*512
    float* ohf   = xh  + (size_t)NN * 512;       // N*8
    float* sa    = ohf + (size_t)NN * OHF;       // N*4
    float* ra    = sa  + (size_t)NN * NH;        // N*4
    int* csr_off = (int*)(ra + (size_t)NN * NH); // N+1
    int* csr_e   = csr_off + NN + 1;             // NET

    k_sortconv<<<NN, 256, 0, stream>>>(onehot, c1w, c1b, c2w, c2b, fcw, fcb, ohf);
    k_csr<<<1, 1024, 0, stream>>>(dst, csr_off, csr_e);
    k_xh<<<NN / 4, 256, 0, stream>>>(x, ohf, lin_w, att_l, att_r, xh, sa, ra);
    k_agg<<<NN, 256, 0, stream>>>(src, csr_off, csr_e, sa, ra, xh, onehot,
                                  bias, out_x, out_oh);
}